// Round 13
// baseline (770.329 us; speedup 1.0000x reference)
//
#include <hip/hip_runtime.h>
#include <hip/hip_fp16.h>
#include <stdint.h>

typedef _Float16 f16;
typedef _Float16 f16x8 __attribute__((ext_vector_type(8)));
typedef _Float16 f16x4 __attribute__((ext_vector_type(4)));
typedef float f32x4 __attribute__((ext_vector_type(4)));

#define MFMA16(a, b, c) __builtin_amdgcn_mfma_f32_16x16x32_f16(a, b, c, 0, 0, 0)

constexpr int BB   = 16;
constexpr int NN   = 596;
constexpr int CC   = 768;
constexpr int HH   = 12;
constexpr int DH   = 64;
constexpr int NCLS = 20;
constexpr int BH   = BB * HH;   // 192
constexpr int NP   = 608;       // seq padded to multiple of 32
constexpr int MM   = BB * NN;   // 9536
constexpr int MMP  = 9600;      // M padded to multiple of 128
constexpr int K3C  = 3 * CC;    // 2304
constexpr int NT   = NP / 16;   // 38 col tiles
constexpr int TPW  = 10;        // col tiles per wave (4 waves: 10/10/10/8)
constexpr int NWG  = NT * BH;   // 7296 = 8 * 912

// q pre-scale: Dh^-0.5 * log2(e), so attn uses exp2 (raw v_exp_f32)
#define QSCALE 0.18033688011112042f

// direct global->LDS DMA, 16B per lane, LDS dest = wave-uniform base + lane*16
__device__ __forceinline__ void gload16(const f16* g, f16* l) {
  __builtin_amdgcn_global_load_lds(
      (const __attribute__((address_space(1))) void*)g,
      (__attribute__((address_space(3))) void*)l, 16, 0, 0);
}

// ---------------------------------------------------------------------------
// K0: fused prep: wqkv^T, wproj^T (fp16), x->fp16 (padded), zero q/k/vT pads.
// ---------------------------------------------------------------------------
__global__ __launch_bounds__(256) void prep(
    const float* __restrict__ w_qkv, const float* __restrict__ w_proj,
    const float* __restrict__ x, f16* __restrict__ wqkvT,
    f16* __restrict__ wprojT, f16* __restrict__ x16, f16* __restrict__ q,
    f16* __restrict__ k, f16* __restrict__ vT) {
  __shared__ float t[32][33];
  int b = blockIdx.x;
  if (b < 1728 + 576) {  // transposes
    const float* src = b < 1728 ? w_qkv : w_proj;
    f16* dst = b < 1728 ? wqkvT : wprojT;
    int Ccols = b < 1728 ? K3C : CC;
    int bi = b < 1728 ? b : b - 1728;
    int nbx = Ccols / 32;
    int tile_c = (bi % nbx) * 32, tile_r = (bi / nbx) * 32;
    int tr = threadIdx.x & 31, tg = threadIdx.x >> 5;
#pragma unroll
    for (int i = 0; i < 4; i++)
      t[tg + i * 8][tr] = src[(size_t)(tile_r + tg + i * 8) * Ccols + tile_c + tr];
    __syncthreads();
#pragma unroll
    for (int i = 0; i < 4; i++)
      dst[(size_t)(tile_c + tg + i * 8) * CC + tile_r + tr] =
          (f16)t[tr][tg + i * 8];
    return;
  }
  b -= 1728 + 576;
  if (b < 3600) {  // convert x
    size_t idx = ((size_t)b * 256 + threadIdx.x) * 8;
    f16x8 h;
    if (idx < (size_t)MM * CC) {
      float4 v0 = *reinterpret_cast<const float4*>(&x[idx]);
      float4 v1 = *reinterpret_cast<const float4*>(&x[idx + 4]);
      h[0] = (f16)v0.x; h[1] = (f16)v0.y; h[2] = (f16)v0.z; h[3] = (f16)v0.w;
      h[4] = (f16)v1.x; h[5] = (f16)v1.y; h[6] = (f16)v1.z; h[7] = (f16)v1.w;
    } else {
      h = (f16x8){0, 0, 0, 0, 0, 0, 0, 0};
    }
    *reinterpret_cast<f16x8*>(&x16[idx]) = h;
    return;
  }
  b -= 3600;  // zero pads, b = bh
  int tid = threadIdx.x;
  for (int i = tid; i < 12 * DH; i += 256) {
    int n = NN + (i >> 6), d = i & 63;
    q[((size_t)b * NP + n) * DH + d] = (f16)0.f;
    k[((size_t)b * NP + n) * DH + d] = (f16)0.f;
  }
  for (int i = tid; i < DH * 12; i += 256) {
    int d = i / 12, n = NN + (i % 12);
    vT[((size_t)b * DH + d) * NP + n] = (f16)0.f;
  }
}

// ---------------------------------------------------------------------------
// K1: QKV GEMM, 128x128x64 tiles, global_load_lds staging + XOR swizzle.
// ---------------------------------------------------------------------------
__global__ __launch_bounds__(256) void qkv_gemm(
    const f16* __restrict__ x16, const f16* __restrict__ wT,
    const float* __restrict__ bias, f16* __restrict__ q,
    f16* __restrict__ karr, f16* __restrict__ vT) {
  __shared__ f16 As[128 * 64];
  __shared__ f16 Bs[128 * 64];
  int bn = blockIdx.x, bm = blockIdx.y;
  int tid = threadIdx.x;
  int wid = tid >> 6, lane = tid & 63;
  int wm = wid >> 1, wn = wid & 1;
  int lr = lane & 15, lg = lane >> 4;
  int srcChunk = (lane & 7) ^ (lane >> 3);

  const f16* gA = &x16[((size_t)bm * 128 + (lane >> 3)) * CC + srcChunk * 8];
  const f16* gB = &wT[((size_t)bn * 128 + (lane >> 3)) * CC + srcChunk * 8];

  f32x4 acc[4][4] = {};
  for (int k0 = 0; k0 < CC; k0 += 64) {
#pragma unroll
    for (int j = 0; j < 4; j++) {
      int r0 = (wid * 4 + j) * 8;
      gload16(gA + (size_t)r0 * CC + k0, &As[r0 * 64]);
      gload16(gB + (size_t)r0 * CC + k0, &Bs[r0 * 64]);
    }
    __syncthreads();
#pragma unroll
    for (int ks = 0; ks < 2; ks++) {
      f16x8 a[4], b[4];
#pragma unroll
      for (int mt = 0; mt < 4; mt++)
        a[mt] = *reinterpret_cast<const f16x8*>(
            &As[(wm * 64 + mt * 16 + lr) * 64 + ((ks * 4 + lg) ^ (lr & 7)) * 8]);
#pragma unroll
      for (int nt = 0; nt < 4; nt++)
        b[nt] = *reinterpret_cast<const f16x8*>(
            &Bs[(wn * 64 + nt * 16 + lr) * 64 + ((ks * 4 + lg) ^ (lr & 7)) * 8]);
#pragma unroll
      for (int mt = 0; mt < 4; mt++)
#pragma unroll
        for (int nt = 0; nt < 4; nt++)
          acc[mt][nt] = MFMA16(a[mt], b[nt], acc[mt][nt]);
    }
    __syncthreads();
  }

  int which = bn / 6;          // 0=q 1=k 2=v  (768 = 6*128 -> aligned)
  int hbase = (bn % 6) * 128;
#pragma unroll
  for (int mt = 0; mt < 4; mt++)
#pragma unroll
    for (int nt = 0; nt < 4; nt++) {
      int colL = wn * 64 + nt * 16 + lr;
      float bi = bias[bn * 128 + colL];
      int hcol = hbase + colL;
      int h = hcol >> 6, dcol = hcol & 63;
#pragma unroll
      for (int i = 0; i < 4; i++) {
        int m = bm * 128 + wm * 64 + mt * 16 + lg * 4 + i;
        if (m < MM) {
          float val = acc[mt][nt][i] + bi;
          int b = m / NN, n = m - b * NN;
          size_t bh = (size_t)b * HH + h;
          if (which == 0)
            q[(bh * NP + n) * DH + dcol] = (f16)(val * QSCALE);
          else if (which == 1)
            karr[(bh * NP + n) * DH + dcol] = (f16)val;
          else
            vT[(bh * DH + dcol) * NP + n] = (f16)val;
        }
      }
    }
}

// ---------------------------------------------------------------------------
// K2: fused attention, PHASE-ABLATION template (diagnostic round).
// VARIANT 0: score+exp2+P(LDS)+sums+inv only (asm keep-alive, no gl writes)
// VARIANT 1: V0 + PV + ctx (no weights write)
// VARIANT 2: full kernel (launched last -> correct final state)
// REP amplifies the grid (duplicate wgid copies write identical values) so
// each dispatch exceeds the ~175us harness fills and shows in rocprof top-5.
// ---------------------------------------------------------------------------
template <int VARIANT, int REP>
__global__ __launch_bounds__(256) void attn_kernel(
    const f16* __restrict__ q, const f16* __restrict__ karr,
    const f16* __restrict__ vT, float* __restrict__ weights,
    f16* __restrict__ ctx) {
  __shared__ f16 P[16][616];  // unnormalized exp2(scores), [q-row][k-col]
  __shared__ float redS[4][16];
  __shared__ float invA_lds[16];
  __shared__ float invB_lds[16];

  int bid = (int)blockIdx.x / REP;
  int wgid = (bid & 7) * (NWG / 8) + (bid >> 3);  // bijective XCD swizzle
  int bh = wgid / NT, qt = wgid - bh * NT;

  int tid = threadIdx.x, wid = tid >> 6, lane = tid & 63;
  int lr = lane & 15, lg = lane >> 4;
  int qbase = qt * 16;

  const f16* qrowp = q + ((size_t)bh * NP + qbase + lr) * DH;
  f16x8 a0 = *reinterpret_cast<const f16x8*>(&qrowp[lg * 8]);
  f16x8 a1 = *reinterpret_cast<const f16x8*>(&qrowp[32 + lg * 8]);

  const f16* kb = karr + (size_t)bh * NP * DH;
  float psA = 0.f, psB = 0.f;  // per-lane partials for q-row lr
#pragma unroll
  for (int t = 0; t < TPW; t++) {
    int ct = wid * TPW + t;
    int ctc = ct < NT ? ct : NT - 1;  // clamped (safe) address
    bool live = ct < NT;
    const f16* krp = &kb[(size_t)(ctc * 16 + lr) * DH];
    f16x8 b0 = *reinterpret_cast<const f16x8*>(&krp[lg * 8]);
    f16x8 b1 = *reinterpret_cast<const f16x8*>(&krp[32 + lg * 8]);
    f32x4 acc = {};
    acc = MFMA16(b0, a0, acc);   // S^T: row = k-col, col = q-row
    acc = MFMA16(b1, a1, acc);
    f16x4 pk;
#pragma unroll
    for (int i = 0; i < 4; i++) {
      int col = ct * 16 + lg * 4 + i;   // k column
      bool inA = col < NCLS;
      bool valid = live && (col < NN);
      float e = valid ? __builtin_amdgcn_exp2f(acc[i]) : 0.f;
      if (inA) psA += e; else psB += e;
      pk[i] = (f16)e;
    }
    if (live)
      *reinterpret_cast<f16x4*>(&P[lr][ct * 16 + lg * 4]) = pk;
  }
  // reduce across the 4 lanes sharing q-row lr (lanes lr, lr+16, lr+32, lr+48)
  psA += __shfl_xor(psA, 16);
  psA += __shfl_xor(psA, 32);
  psB += __shfl_xor(psB, 16);
  psB += __shfl_xor(psB, 32);
  if (lane < 16) {
    redS[wid][lr] = psB;
    if (wid == 0) invA_lds[lr] = 1.0f / psA;  // cls cols live in wave 0
  }
  __syncthreads();
  if (wid == 2 && lane < 16)
    invB_lds[lr] =
        1.0f / (redS[0][lr] + redS[1][lr] + redS[2][lr] + redS[3][lr]);
  __syncthreads();

  if constexpr (VARIANT == 0) {
    // keep the whole score phase live without any global traffic (rule #17)
    float chk = invA_lds[lr] + invB_lds[lr];
    float p0 = (float)P[lr][lane];
    float p1 = (float)P[lr][lane + 544];
    asm volatile("" ::"v"(chk), "v"(p0), "v"(p1));
    return;
  }

  if constexpr (VARIANT >= 2) {
    // weights write: static row-per-thread mapping (16 rows x 16 threads)
    int row = tid >> 4, sub = tid & 15;
    int grow = qbase + row;
    if (grow < NN) {
      float iA = invA_lds[row];
      float iB = invB_lds[row];
      const f16* prow = &P[row][0];
      float* wrow = weights + ((size_t)bh * NN + grow) * NN;
#pragma unroll
      for (int k2 = 0; k2 < 10; k2++) {
        int f4 = sub + 16 * k2;
        if (f4 < NN / 4) {
          float inv = (f4 < 5) ? iA : iB;
          f16x4 pv = *reinterpret_cast<const f16x4*>(&prow[f4 * 4]);
          float4 o4 = {(float)pv[0] * inv, (float)pv[1] * inv,
                       (float)pv[2] * inv, (float)pv[3] * inv};
          *reinterpret_cast<float4*>(&wrow[f4 * 4]) = o4;
        }
      }
    }
  }

  // PV (swapped): D[d][q]; cls part in oA, patch part in oB.
  const f16* vrow = vT + (size_t)bh * DH * NP + (size_t)(wid * 16 + lr) * NP;
  f32x4 oA = {}, oB = {};
  {
    f16x8 pa = *reinterpret_cast<const f16x8*>(&P[lr][lg * 8]);
    f16x8 paA = pa, paB = pa;
#pragma unroll
    for (int j = 0; j < 8; j++) {
      if (lg * 8 + j < NCLS) paB[j] = (f16)0.f;
      else paA[j] = (f16)0.f;
    }
    f16x8 bv = *reinterpret_cast<const f16x8*>(&vrow[lg * 8]);
    oA = MFMA16(bv, paA, oA);
    oB = MFMA16(bv, paB, oB);
  }
#pragma unroll
  for (int j = 1; j < 19; j++) {
    f16x8 bv = *reinterpret_cast<const f16x8*>(&vrow[j * 32 + lg * 8]);
    f16x8 pa = *reinterpret_cast<const f16x8*>(&P[lr][j * 32 + lg * 8]);
    oB = MFMA16(bv, pa, oB);
  }

  // epilogue: lane holds D[d = wid*16 + lg*4 + i][q = lr] -> one 8B store
  int qrow = qbase + lr;
  if (qrow < NN) {
    float iA = invA_lds[lr], iB = invB_lds[lr];
    int b = bh / HH, h = bh - b * HH;
    f16x4 o4;
#pragma unroll
    for (int i = 0; i < 4; i++) o4[i] = (f16)(oA[i] * iA + oB[i] * iB);
    *reinterpret_cast<f16x4*>(
        &ctx[((size_t)b * NN + qrow) * CC + h * DH + wid * 16 + lg * 4]) = o4;
  }
}

// ---------------------------------------------------------------------------
// K3: proj GEMM, 128x128x64 tiles, global_load_lds + XOR swizzle.
// ---------------------------------------------------------------------------
__global__ __launch_bounds__(256) void proj_gemm(
    const f16* __restrict__ ctx, const f16* __restrict__ wT,
    const float* __restrict__ bias, float* __restrict__ out) {
  __shared__ f16 As[128 * 64];
  __shared__ f16 Bs[128 * 64];
  int bn = blockIdx.x, bm = blockIdx.y;
  int tid = threadIdx.x;
  int wid = tid >> 6, lane = tid & 63;
  int wm = wid >> 1, wn = wid & 1;
  int lr = lane & 15, lg = lane >> 4;
  int srcChunk = (lane & 7) ^ (lane >> 3);

  const f16* gA = &ctx[((size_t)bm * 128 + (lane >> 3)) * CC + srcChunk * 8];
  const f16* gB = &wT[((size_t)bn * 128 + (lane >> 3)) * CC + srcChunk * 8];

  f32x4 acc[4][4] = {};
  for (int k0 = 0; k0 < CC; k0 += 64) {
#pragma unroll
    for (int j = 0; j < 4; j++) {
      int r0 = (wid * 4 + j) * 8;
      gload16(gA + (size_t)r0 * CC + k0, &As[r0 * 64]);
      gload16(gB + (size_t)r0 * CC + k0, &Bs[r0 * 64]);
    }
    __syncthreads();
#pragma unroll
    for (int ks = 0; ks < 2; ks++) {
      f16x8 a[4], b[4];
#pragma unroll
      for (int mt = 0; mt < 4; mt++)
        a[mt] = *reinterpret_cast<const f16x8*>(
            &As[(wm * 64 + mt * 16 + lr) * 64 + ((ks * 4 + lg) ^ (lr & 7)) * 8]);
#pragma unroll
      for (int nt = 0; nt < 4; nt++)
        b[nt] = *reinterpret_cast<const f16x8*>(
            &Bs[(wn * 64 + nt * 16 + lr) * 64 + ((ks * 4 + lg) ^ (lr & 7)) * 8]);
#pragma unroll
      for (int mt = 0; mt < 4; mt++)
#pragma unroll
        for (int nt = 0; nt < 4; nt++)
          acc[mt][nt] = MFMA16(a[mt], b[nt], acc[mt][nt]);
    }
    __syncthreads();
  }
#pragma unroll
  for (int mt = 0; mt < 4; mt++)
#pragma unroll
    for (int nt = 0; nt < 4; nt++) {
      int colL = wn * 64 + nt * 16 + lr;
      float bi = bias[bn * 128 + colL];
#pragma unroll
      for (int i = 0; i < 4; i++) {
        int m = bm * 128 + wm * 64 + mt * 16 + lg * 4 + i;
        if (m < MM)
          out[(size_t)m * CC + bn * 128 + colL] = acc[mt][nt][i] + bi;
      }
    }
}

// ---------------------------------------------------------------------------
extern "C" void kernel_launch(void* const* d_in, const int* in_sizes, int n_in,
                              void* d_out, int out_size, void* d_ws,
                              size_t ws_size, hipStream_t stream) {
  const float* x      = (const float*)d_in[0];
  const float* w_qkv  = (const float*)d_in[1];
  const float* b_qkv  = (const float*)d_in[2];
  const float* w_proj = (const float*)d_in[3];
  const float* b_proj = (const float*)d_in[4];

  float* out     = (float*)d_out;
  float* weights = out + (size_t)MM * CC;

  f16* p      = (f16*)d_ws;
  f16* wqkvT  = p;  p += (size_t)K3C * CC;
  f16* wprojT = p;  p += (size_t)CC * CC;
  f16* x16    = p;  p += (size_t)MMP * CC;
  f16* qb     = p;  p += (size_t)BH * NP * DH;
  f16* kb     = p;  p += (size_t)BH * NP * DH;
  f16* vT     = p;  p += (size_t)BH * DH * NP;
  f16* ctx    = p;  p += (size_t)MMP * CC;

  prep<<<1728 + 576 + 3600 + 192, 256, 0, stream>>>(w_qkv, w_proj, x, wqkvT,
                                                    wprojT, x16, qb, kb, vT);
  qkv_gemm<<<dim3(K3C / 128, MMP / 128), 256, 0, stream>>>(x16, wqkvT, b_qkv,
                                                           qb, kb, vT);
  // --- phase ablation (diagnostic): V0 score-only x3, V1 no-weights x2,
  // --- V2 full x2 (last, produces the correct final output state)
  attn_kernel<0, 3><<<3 * NWG, 256, 0, stream>>>(qb, kb, vT, weights, ctx);
  attn_kernel<1, 2><<<2 * NWG, 256, 0, stream>>>(qb, kb, vT, weights, ctx);
  attn_kernel<2, 2><<<2 * NWG, 256, 0, stream>>>(qb, kb, vT, weights, ctx);
  proj_gemm<<<dim3(CC / 128, MMP / 128), 256, 0, stream>>>(ctx, wprojT, b_proj,
                                                           out);
}

// Round 14
// 215.869 us; speedup vs baseline: 3.5685x; 3.5685x over previous
//
#include <hip/hip_runtime.h>
#include <hip/hip_fp16.h>
#include <stdint.h>

typedef _Float16 f16;
typedef _Float16 f16x8 __attribute__((ext_vector_type(8)));
typedef _Float16 f16x4 __attribute__((ext_vector_type(4)));
typedef float f32x4 __attribute__((ext_vector_type(4)));

#define MFMA16(a, b, c) __builtin_amdgcn_mfma_f32_16x16x32_f16(a, b, c, 0, 0, 0)

constexpr int BB   = 16;
constexpr int NN   = 596;
constexpr int CC   = 768;
constexpr int HH   = 12;
constexpr int DH   = 64;
constexpr int NCLS = 20;
constexpr int BH   = BB * HH;   // 192
constexpr int NP   = 608;       // seq padded to multiple of 32
constexpr int MM   = BB * NN;   // 9536
constexpr int MMP  = 9600;      // M padded to multiple of 128
constexpr int K3C  = 3 * CC;    // 2304
constexpr int NT   = NP / 16;   // 38 col tiles
constexpr int TPW  = 10;        // col tiles per wave (4 waves: 10/10/10/8)
constexpr int NQT  = NP / 32;   // 19 q-tiles of 32 rows
constexpr int NWG32 = NQT * BH; // 3648 = 8 * 456

// q pre-scale: Dh^-0.5 * log2(e), so attn uses exp2 (raw v_exp_f32)
#define QSCALE 0.18033688011112042f

// direct global->LDS DMA, 16B per lane, LDS dest = wave-uniform base + lane*16
__device__ __forceinline__ void gload16(const f16* g, f16* l) {
  __builtin_amdgcn_global_load_lds(
      (const __attribute__((address_space(1))) void*)g,
      (__attribute__((address_space(3))) void*)l, 16, 0, 0);
}

// ---------------------------------------------------------------------------
// K0: fused prep: wqkv^T, wproj^T (fp16), x->fp16 (padded), zero q/k/vT pads.
// ---------------------------------------------------------------------------
__global__ __launch_bounds__(256) void prep(
    const float* __restrict__ w_qkv, const float* __restrict__ w_proj,
    const float* __restrict__ x, f16* __restrict__ wqkvT,
    f16* __restrict__ wprojT, f16* __restrict__ x16, f16* __restrict__ q,
    f16* __restrict__ k, f16* __restrict__ vT) {
  __shared__ float t[32][33];
  int b = blockIdx.x;
  if (b < 1728 + 576) {  // transposes
    const float* src = b < 1728 ? w_qkv : w_proj;
    f16* dst = b < 1728 ? wqkvT : wprojT;
    int Ccols = b < 1728 ? K3C : CC;
    int bi = b < 1728 ? b : b - 1728;
    int nbx = Ccols / 32;
    int tile_c = (bi % nbx) * 32, tile_r = (bi / nbx) * 32;
    int tr = threadIdx.x & 31, tg = threadIdx.x >> 5;
#pragma unroll
    for (int i = 0; i < 4; i++)
      t[tg + i * 8][tr] = src[(size_t)(tile_r + tg + i * 8) * Ccols + tile_c + tr];
    __syncthreads();
#pragma unroll
    for (int i = 0; i < 4; i++)
      dst[(size_t)(tile_c + tg + i * 8) * CC + tile_r + tr] =
          (f16)t[tr][tg + i * 8];
    return;
  }
  b -= 1728 + 576;
  if (b < 3600) {  // convert x
    size_t idx = ((size_t)b * 256 + threadIdx.x) * 8;
    f16x8 h;
    if (idx < (size_t)MM * CC) {
      float4 v0 = *reinterpret_cast<const float4*>(&x[idx]);
      float4 v1 = *reinterpret_cast<const float4*>(&x[idx + 4]);
      h[0] = (f16)v0.x; h[1] = (f16)v0.y; h[2] = (f16)v0.z; h[3] = (f16)v0.w;
      h[4] = (f16)v1.x; h[5] = (f16)v1.y; h[6] = (f16)v1.z; h[7] = (f16)v1.w;
    } else {
      h = (f16x8){0, 0, 0, 0, 0, 0, 0, 0};
    }
    *reinterpret_cast<f16x8*>(&x16[idx]) = h;
    return;
  }
  b -= 3600;  // zero pads, b = bh
  int tid = threadIdx.x;
  for (int i = tid; i < 12 * DH; i += 256) {
    int n = NN + (i >> 6), d = i & 63;
    q[((size_t)b * NP + n) * DH + d] = (f16)0.f;
    k[((size_t)b * NP + n) * DH + d] = (f16)0.f;
  }
  for (int i = tid; i < DH * 12; i += 256) {
    int d = i / 12, n = NN + (i % 12);
    vT[((size_t)b * DH + d) * NP + n] = (f16)0.f;
  }
}

// ---------------------------------------------------------------------------
// K1: QKV GEMM, 128x128x64 tiles, global_load_lds staging + XOR swizzle.
// ---------------------------------------------------------------------------
__global__ __launch_bounds__(256) void qkv_gemm(
    const f16* __restrict__ x16, const f16* __restrict__ wT,
    const float* __restrict__ bias, f16* __restrict__ q,
    f16* __restrict__ karr, f16* __restrict__ vT) {
  __shared__ f16 As[128 * 64];
  __shared__ f16 Bs[128 * 64];
  int bn = blockIdx.x, bm = blockIdx.y;
  int tid = threadIdx.x;
  int wid = tid >> 6, lane = tid & 63;
  int wm = wid >> 1, wn = wid & 1;
  int lr = lane & 15, lg = lane >> 4;
  int srcChunk = (lane & 7) ^ (lane >> 3);

  const f16* gA = &x16[((size_t)bm * 128 + (lane >> 3)) * CC + srcChunk * 8];
  const f16* gB = &wT[((size_t)bn * 128 + (lane >> 3)) * CC + srcChunk * 8];

  f32x4 acc[4][4] = {};
  for (int k0 = 0; k0 < CC; k0 += 64) {
#pragma unroll
    for (int j = 0; j < 4; j++) {
      int r0 = (wid * 4 + j) * 8;
      gload16(gA + (size_t)r0 * CC + k0, &As[r0 * 64]);
      gload16(gB + (size_t)r0 * CC + k0, &Bs[r0 * 64]);
    }
    __syncthreads();
#pragma unroll
    for (int ks = 0; ks < 2; ks++) {
      f16x8 a[4], b[4];
#pragma unroll
      for (int mt = 0; mt < 4; mt++)
        a[mt] = *reinterpret_cast<const f16x8*>(
            &As[(wm * 64 + mt * 16 + lr) * 64 + ((ks * 4 + lg) ^ (lr & 7)) * 8]);
#pragma unroll
      for (int nt = 0; nt < 4; nt++)
        b[nt] = *reinterpret_cast<const f16x8*>(
            &Bs[(wn * 64 + nt * 16 + lr) * 64 + ((ks * 4 + lg) ^ (lr & 7)) * 8]);
#pragma unroll
      for (int mt = 0; mt < 4; mt++)
#pragma unroll
        for (int nt = 0; nt < 4; nt++)
          acc[mt][nt] = MFMA16(a[mt], b[nt], acc[mt][nt]);
    }
    __syncthreads();
  }

  int which = bn / 6;          // 0=q 1=k 2=v  (768 = 6*128 -> aligned)
  int hbase = (bn % 6) * 128;
#pragma unroll
  for (int mt = 0; mt < 4; mt++)
#pragma unroll
    for (int nt = 0; nt < 4; nt++) {
      int colL = wn * 64 + nt * 16 + lr;
      float bi = bias[bn * 128 + colL];
      int hcol = hbase + colL;
      int h = hcol >> 6, dcol = hcol & 63;
#pragma unroll
      for (int i = 0; i < 4; i++) {
        int m = bm * 128 + wm * 64 + mt * 16 + lg * 4 + i;
        if (m < MM) {
          float val = acc[mt][nt][i] + bi;
          int b = m / NN, n = m - b * NN;
          size_t bh = (size_t)b * HH + h;
          if (which == 0)
            q[(bh * NP + n) * DH + dcol] = (f16)(val * QSCALE);
          else if (which == 1)
            karr[(bh * NP + n) * DH + dcol] = (f16)val;
          else
            vT[(bh * DH + dcol) * NP + n] = (f16)val;
        }
      }
    }
}

// ---------------------------------------------------------------------------
// K2: fused attention, 32 q-rows per WAVE (register reuse): each loaded K
// fragment pair feeds TWO MFMAs (row-groups 0/1), each V fragment feeds two
// PV MFMAs -> global load instructions per output halve (the R13 ablation
// showed the score phase's read side is the binding cost; R12's version
// duplicated loads across waves and was neutral).
// Grid: 3648, block 256 (4 waves).
// ---------------------------------------------------------------------------
__global__ __launch_bounds__(256) void attn_kernel(
    const f16* __restrict__ q, const f16* __restrict__ karr,
    const f16* __restrict__ vT, float* __restrict__ weights,
    f16* __restrict__ ctx) {
  __shared__ f16 P[2][16][616];  // unnormalized exp2(scores), [rg][row][col]
  __shared__ float redS[2][4][16];
  __shared__ float invA_lds[2][16];
  __shared__ float invB_lds[2][16];

  int bid = blockIdx.x;
  int wgid = (bid & 7) * (NWG32 / 8) + (bid >> 3);  // bijective XCD swizzle
  int bh = wgid / NQT, qt = wgid - bh * NQT;

  int tid = threadIdx.x, wid = tid >> 6, lane = tid & 63;
  int lr = lane & 15, lg = lane >> 4;
  int qbase = qt * 32;

  // q fragments for BOTH 16-row groups (rows qbase+lr and qbase+16+lr)
  const f16* qr0 = q + ((size_t)bh * NP + qbase + lr) * DH;
  const f16* qr1 = qr0 + 16 * DH;
  f16x8 a0 = *reinterpret_cast<const f16x8*>(&qr0[lg * 8]);
  f16x8 a1 = *reinterpret_cast<const f16x8*>(&qr0[32 + lg * 8]);
  f16x8 a2 = *reinterpret_cast<const f16x8*>(&qr1[lg * 8]);
  f16x8 a3 = *reinterpret_cast<const f16x8*>(&qr1[32 + lg * 8]);

  const f16* kb = karr + (size_t)bh * NP * DH;
  float psA0 = 0.f, psB0 = 0.f, psA1 = 0.f, psB1 = 0.f;
#pragma unroll
  for (int t = 0; t < TPW; t++) {
    int ct = wid * TPW + t;
    int ctc = ct < NT ? ct : NT - 1;  // clamped (safe) address
    bool live = ct < NT;
    const f16* krp = &kb[(size_t)(ctc * 16 + lr) * DH];
    f16x8 b0 = *reinterpret_cast<const f16x8*>(&krp[lg * 8]);
    f16x8 b1 = *reinterpret_cast<const f16x8*>(&krp[32 + lg * 8]);
    f32x4 acc0 = {}, acc1 = {};
    acc0 = MFMA16(b0, a0, acc0);   // S^T: row = k-col, col = q-row (rg0)
    acc0 = MFMA16(b1, a1, acc0);
    acc1 = MFMA16(b0, a2, acc1);   // rg1 reuses the SAME b0/b1
    acc1 = MFMA16(b1, a3, acc1);
    f16x4 pk0, pk1;
#pragma unroll
    for (int i = 0; i < 4; i++) {
      int col = ct * 16 + lg * 4 + i;   // k column
      bool inA = col < NCLS;
      bool valid = live && (col < NN);
      float e0 = valid ? __builtin_amdgcn_exp2f(acc0[i]) : 0.f;
      float e1 = valid ? __builtin_amdgcn_exp2f(acc1[i]) : 0.f;
      if (inA) { psA0 += e0; psA1 += e1; }
      else     { psB0 += e0; psB1 += e1; }
      pk0[i] = (f16)e0;
      pk1[i] = (f16)e1;
    }
    if (live) {
      *reinterpret_cast<f16x4*>(&P[0][lr][ct * 16 + lg * 4]) = pk0;
      *reinterpret_cast<f16x4*>(&P[1][lr][ct * 16 + lg * 4]) = pk1;
    }
  }
  // reduce across the 4 lanes sharing q-row lr (lanes lr, lr+16, lr+32, lr+48)
  psA0 += __shfl_xor(psA0, 16); psA0 += __shfl_xor(psA0, 32);
  psB0 += __shfl_xor(psB0, 16); psB0 += __shfl_xor(psB0, 32);
  psA1 += __shfl_xor(psA1, 16); psA1 += __shfl_xor(psA1, 32);
  psB1 += __shfl_xor(psB1, 16); psB1 += __shfl_xor(psB1, 32);
  if (lane < 16) {
    redS[0][wid][lr] = psB0;
    redS[1][wid][lr] = psB1;
    if (wid == 0) {  // cls cols live entirely in wave 0
      invA_lds[0][lr] = 1.0f / psA0;
      invA_lds[1][lr] = 1.0f / psA1;
    }
  }
  __syncthreads();
  if (wid == 2 && lane < 16) {
    invB_lds[0][lr] = 1.0f / (redS[0][0][lr] + redS[0][1][lr] +
                              redS[0][2][lr] + redS[0][3][lr]);
    invB_lds[1][lr] = 1.0f / (redS[1][0][lr] + redS[1][1][lr] +
                              redS[1][2][lr] + redS[1][3][lr]);
  }
  __syncthreads();

  // weights write: static mapping, each thread handles one row per row-group
  {
    int row = tid >> 4, sub = tid & 15;
#pragma unroll
    for (int g = 0; g < 2; g++) {
      int grow = qbase + g * 16 + row;
      if (grow < NN) {
        float iA = invA_lds[g][row];
        float iB = invB_lds[g][row];
        const f16* prow = &P[g][row][0];
        float* wrow = weights + ((size_t)bh * NN + grow) * NN;
#pragma unroll
        for (int k2 = 0; k2 < 10; k2++) {
          int f4 = sub + 16 * k2;
          if (f4 < NN / 4) {
            float inv = (f4 < 5) ? iA : iB;
            f16x4 pv = *reinterpret_cast<const f16x4*>(&prow[f4 * 4]);
            float4 o4 = {(float)pv[0] * inv, (float)pv[1] * inv,
                         (float)pv[2] * inv, (float)pv[3] * inv};
            *reinterpret_cast<float4*>(&wrow[f4 * 4]) = o4;
          }
        }
      }
    }
  }

  // PV (swapped): D[d][q]; each V fragment feeds BOTH row-groups' MFMAs.
  const f16* vrow = vT + (size_t)bh * DH * NP + (size_t)(wid * 16 + lr) * NP;
  f32x4 oA0 = {}, oB0 = {}, oA1 = {}, oB1 = {};
  {
    f16x8 pa0 = *reinterpret_cast<const f16x8*>(&P[0][lr][lg * 8]);
    f16x8 pa1 = *reinterpret_cast<const f16x8*>(&P[1][lr][lg * 8]);
    f16x8 pa0A = pa0, pa0B = pa0, pa1A = pa1, pa1B = pa1;
#pragma unroll
    for (int j = 0; j < 8; j++) {
      if (lg * 8 + j < NCLS) { pa0B[j] = (f16)0.f; pa1B[j] = (f16)0.f; }
      else                   { pa0A[j] = (f16)0.f; pa1A[j] = (f16)0.f; }
    }
    f16x8 bv = *reinterpret_cast<const f16x8*>(&vrow[lg * 8]);
    oA0 = MFMA16(bv, pa0A, oA0);
    oB0 = MFMA16(bv, pa0B, oB0);
    oA1 = MFMA16(bv, pa1A, oA1);
    oB1 = MFMA16(bv, pa1B, oB1);
  }
#pragma unroll
  for (int j = 1; j < 19; j++) {
    f16x8 bv = *reinterpret_cast<const f16x8*>(&vrow[j * 32 + lg * 8]);
    f16x8 pa0 = *reinterpret_cast<const f16x8*>(&P[0][lr][j * 32 + lg * 8]);
    f16x8 pa1 = *reinterpret_cast<const f16x8*>(&P[1][lr][j * 32 + lg * 8]);
    oB0 = MFMA16(bv, pa0, oB0);
    oB1 = MFMA16(bv, pa1, oB1);
  }

  // epilogue: lane holds D[d = wid*16 + lg*4 + i][q = lr] for both groups
  int b = bh / HH, h = bh - b * HH;
  {
    int qrow = qbase + lr;
    if (qrow < NN) {
      float iA = invA_lds[0][lr], iB = invB_lds[0][lr];
      f16x4 o4;
#pragma unroll
      for (int i = 0; i < 4; i++) o4[i] = (f16)(oA0[i] * iA + oB0[i] * iB);
      *reinterpret_cast<f16x4*>(
          &ctx[((size_t)b * NN + qrow) * CC + h * DH + wid * 16 + lg * 4]) = o4;
    }
  }
  {
    int qrow = qbase + 16 + lr;
    if (qrow < NN) {
      float iA = invA_lds[1][lr], iB = invB_lds[1][lr];
      f16x4 o4;
#pragma unroll
      for (int i = 0; i < 4; i++) o4[i] = (f16)(oA1[i] * iA + oB1[i] * iB);
      *reinterpret_cast<f16x4*>(
          &ctx[((size_t)b * NN + qrow) * CC + h * DH + wid * 16 + lg * 4]) = o4;
    }
  }
}

// ---------------------------------------------------------------------------
// K3: proj GEMM, 128x128x64 tiles, global_load_lds + XOR swizzle.
// ---------------------------------------------------------------------------
__global__ __launch_bounds__(256) void proj_gemm(
    const f16* __restrict__ ctx, const f16* __restrict__ wT,
    const float* __restrict__ bias, float* __restrict__ out) {
  __shared__ f16 As[128 * 64];
  __shared__ f16 Bs[128 * 64];
  int bn = blockIdx.x, bm = blockIdx.y;
  int tid = threadIdx.x;
  int wid = tid >> 6, lane = tid & 63;
  int wm = wid >> 1, wn = wid & 1;
  int lr = lane & 15, lg = lane >> 4;
  int srcChunk = (lane & 7) ^ (lane >> 3);

  const f16* gA = &ctx[((size_t)bm * 128 + (lane >> 3)) * CC + srcChunk * 8];
  const f16* gB = &wT[((size_t)bn * 128 + (lane >> 3)) * CC + srcChunk * 8];

  f32x4 acc[4][4] = {};
  for (int k0 = 0; k0 < CC; k0 += 64) {
#pragma unroll
    for (int j = 0; j < 4; j++) {
      int r0 = (wid * 4 + j) * 8;
      gload16(gA + (size_t)r0 * CC + k0, &As[r0 * 64]);
      gload16(gB + (size_t)r0 * CC + k0, &Bs[r0 * 64]);
    }
    __syncthreads();
#pragma unroll
    for (int ks = 0; ks < 2; ks++) {
      f16x8 a[4], b[4];
#pragma unroll
      for (int mt = 0; mt < 4; mt++)
        a[mt] = *reinterpret_cast<const f16x8*>(
            &As[(wm * 64 + mt * 16 + lr) * 64 + ((ks * 4 + lg) ^ (lr & 7)) * 8]);
#pragma unroll
      for (int nt = 0; nt < 4; nt++)
        b[nt] = *reinterpret_cast<const f16x8*>(
            &Bs[(wn * 64 + nt * 16 + lr) * 64 + ((ks * 4 + lg) ^ (lr & 7)) * 8]);
#pragma unroll
      for (int mt = 0; mt < 4; mt++)
#pragma unroll
        for (int nt = 0; nt < 4; nt++)
          acc[mt][nt] = MFMA16(a[mt], b[nt], acc[mt][nt]);
    }
    __syncthreads();
  }
#pragma unroll
  for (int mt = 0; mt < 4; mt++)
#pragma unroll
    for (int nt = 0; nt < 4; nt++) {
      int colL = wn * 64 + nt * 16 + lr;
      float bi = bias[bn * 128 + colL];
#pragma unroll
      for (int i = 0; i < 4; i++) {
        int m = bm * 128 + wm * 64 + mt * 16 + lg * 4 + i;
        if (m < MM)
          out[(size_t)m * CC + bn * 128 + colL] = acc[mt][nt][i] + bi;
      }
    }
}

// ---------------------------------------------------------------------------
extern "C" void kernel_launch(void* const* d_in, const int* in_sizes, int n_in,
                              void* d_out, int out_size, void* d_ws,
                              size_t ws_size, hipStream_t stream) {
  const float* x      = (const float*)d_in[0];
  const float* w_qkv  = (const float*)d_in[1];
  const float* b_qkv  = (const float*)d_in[2];
  const float* w_proj = (const float*)d_in[3];
  const float* b_proj = (const float*)d_in[4];

  float* out     = (float*)d_out;
  float* weights = out + (size_t)MM * CC;

  f16* p      = (f16*)d_ws;
  f16* wqkvT  = p;  p += (size_t)K3C * CC;
  f16* wprojT = p;  p += (size_t)CC * CC;
  f16* x16    = p;  p += (size_t)MMP * CC;
  f16* qb     = p;  p += (size_t)BH * NP * DH;
  f16* kb     = p;  p += (size_t)BH * NP * DH;
  f16* vT     = p;  p += (size_t)BH * DH * NP;
  f16* ctx    = p;  p += (size_t)MMP * CC;

  prep<<<1728 + 576 + 3600 + 192, 256, 0, stream>>>(w_qkv, w_proj, x, wqkvT,
                                                    wprojT, x16, qb, kb, vT);
  qkv_gemm<<<dim3(K3C / 128, MMP / 128), 256, 0, stream>>>(x16, wqkvT, b_qkv,
                                                           qb, kb, vT);
  attn_kernel<<<NWG32, 256, 0, stream>>>(qb, kb, vT, weights, ctx);
  proj_gemm<<<dim3(CC / 128, MMP / 128), 256, 0, stream>>>(ctx, wprojT, b_proj,
                                                           out);
}

// Round 15
// 215.750 us; speedup vs baseline: 3.5705x; 1.0006x over previous
//
#include <hip/hip_runtime.h>
#include <hip/hip_fp16.h>
#include <stdint.h>

typedef _Float16 f16;
typedef _Float16 f16x8 __attribute__((ext_vector_type(8)));
typedef _Float16 f16x4 __attribute__((ext_vector_type(4)));
typedef float f32x4 __attribute__((ext_vector_type(4)));

#define MFMA16(a, b, c) __builtin_amdgcn_mfma_f32_16x16x32_f16(a, b, c, 0, 0, 0)

constexpr int BB   = 16;
constexpr int NN   = 596;
constexpr int CC   = 768;
constexpr int HH   = 12;
constexpr int DH   = 64;
constexpr int NCLS = 20;
constexpr int BH   = BB * HH;   // 192
constexpr int NP   = 608;       // k/v seq padded to multiple of 32
constexpr int NPQ  = 640;       // q seq padded to multiple of 64
constexpr int MM   = BB * NN;   // 9536
constexpr int MMP  = 9600;      // M padded to multiple of 128
constexpr int K3C  = 3 * CC;    // 2304
constexpr int NT   = NP / 16;   // 38 col tiles
constexpr int TPW  = 10;        // col tiles per wave (4 waves: 10/10/10/8)
constexpr int NQT  = NPQ / 64;  // 10 q-tiles of 64 rows
constexpr int NWG64 = NQT * BH; // 1920 = 8 * 240

// q pre-scale: Dh^-0.5 * log2(e), so attn uses exp2 (raw v_exp_f32)
#define QSCALE 0.18033688011112042f

// direct global->LDS DMA, 16B per lane, LDS dest = wave-uniform base + lane*16
__device__ __forceinline__ void gload16(const f16* g, f16* l) {
  __builtin_amdgcn_global_load_lds(
      (const __attribute__((address_space(1))) void*)g,
      (__attribute__((address_space(3))) void*)l, 16, 0, 0);
}

// ---------------------------------------------------------------------------
// K0: fused prep: wqkv^T, wproj^T (fp16), x->fp16 (padded), zero q/k/vT pads.
// ---------------------------------------------------------------------------
__global__ __launch_bounds__(256) void prep(
    const float* __restrict__ w_qkv, const float* __restrict__ w_proj,
    const float* __restrict__ x, f16* __restrict__ wqkvT,
    f16* __restrict__ wprojT, f16* __restrict__ x16, f16* __restrict__ q,
    f16* __restrict__ k, f16* __restrict__ vT) {
  __shared__ float t[32][33];
  int b = blockIdx.x;
  if (b < 1728 + 576) {  // transposes
    const float* src = b < 1728 ? w_qkv : w_proj;
    f16* dst = b < 1728 ? wqkvT : wprojT;
    int Ccols = b < 1728 ? K3C : CC;
    int bi = b < 1728 ? b : b - 1728;
    int nbx = Ccols / 32;
    int tile_c = (bi % nbx) * 32, tile_r = (bi / nbx) * 32;
    int tr = threadIdx.x & 31, tg = threadIdx.x >> 5;
#pragma unroll
    for (int i = 0; i < 4; i++)
      t[tg + i * 8][tr] = src[(size_t)(tile_r + tg + i * 8) * Ccols + tile_c + tr];
    __syncthreads();
#pragma unroll
    for (int i = 0; i < 4; i++)
      dst[(size_t)(tile_c + tg + i * 8) * CC + tile_r + tr] =
          (f16)t[tr][tg + i * 8];
    return;
  }
  b -= 1728 + 576;
  if (b < 3600) {  // convert x
    size_t idx = ((size_t)b * 256 + threadIdx.x) * 8;
    f16x8 h;
    if (idx < (size_t)MM * CC) {
      float4 v0 = *reinterpret_cast<const float4*>(&x[idx]);
      float4 v1 = *reinterpret_cast<const float4*>(&x[idx + 4]);
      h[0] = (f16)v0.x; h[1] = (f16)v0.y; h[2] = (f16)v0.z; h[3] = (f16)v0.w;
      h[4] = (f16)v1.x; h[5] = (f16)v1.y; h[6] = (f16)v1.z; h[7] = (f16)v1.w;
    } else {
      h = (f16x8){0, 0, 0, 0, 0, 0, 0, 0};
    }
    *reinterpret_cast<f16x8*>(&x16[idx]) = h;
    return;
  }
  b -= 3600;  // zero pads, b = bh
  int tid = threadIdx.x;
  for (int i = tid; i < (NPQ - NN) * DH; i += 256) {  // q: 44 pad rows
    int n = NN + (i >> 6), d = i & 63;
    q[((size_t)b * NPQ + n) * DH + d] = (f16)0.f;
  }
  for (int i = tid; i < 12 * DH; i += 256) {          // k: 12 pad rows
    int n = NN + (i >> 6), d = i & 63;
    k[((size_t)b * NP + n) * DH + d] = (f16)0.f;
  }
  for (int i = tid; i < DH * 12; i += 256) {          // vT: 12 pad cols
    int d = i / 12, n = NN + (i % 12);
    vT[((size_t)b * DH + d) * NP + n] = (f16)0.f;
  }
}

// ---------------------------------------------------------------------------
// K1: QKV GEMM, 128x128x64 tiles, global_load_lds staging + XOR swizzle.
// ---------------------------------------------------------------------------
__global__ __launch_bounds__(256) void qkv_gemm(
    const f16* __restrict__ x16, const f16* __restrict__ wT,
    const float* __restrict__ bias, f16* __restrict__ q,
    f16* __restrict__ karr, f16* __restrict__ vT) {
  __shared__ f16 As[128 * 64];
  __shared__ f16 Bs[128 * 64];
  int bn = blockIdx.x, bm = blockIdx.y;
  int tid = threadIdx.x;
  int wid = tid >> 6, lane = tid & 63;
  int wm = wid >> 1, wn = wid & 1;
  int lr = lane & 15, lg = lane >> 4;
  int srcChunk = (lane & 7) ^ (lane >> 3);

  const f16* gA = &x16[((size_t)bm * 128 + (lane >> 3)) * CC + srcChunk * 8];
  const f16* gB = &wT[((size_t)bn * 128 + (lane >> 3)) * CC + srcChunk * 8];

  f32x4 acc[4][4] = {};
  for (int k0 = 0; k0 < CC; k0 += 64) {
#pragma unroll
    for (int j = 0; j < 4; j++) {
      int r0 = (wid * 4 + j) * 8;
      gload16(gA + (size_t)r0 * CC + k0, &As[r0 * 64]);
      gload16(gB + (size_t)r0 * CC + k0, &Bs[r0 * 64]);
    }
    __syncthreads();
#pragma unroll
    for (int ks = 0; ks < 2; ks++) {
      f16x8 a[4], b[4];
#pragma unroll
      for (int mt = 0; mt < 4; mt++)
        a[mt] = *reinterpret_cast<const f16x8*>(
            &As[(wm * 64 + mt * 16 + lr) * 64 + ((ks * 4 + lg) ^ (lr & 7)) * 8]);
#pragma unroll
      for (int nt = 0; nt < 4; nt++)
        b[nt] = *reinterpret_cast<const f16x8*>(
            &Bs[(wn * 64 + nt * 16 + lr) * 64 + ((ks * 4 + lg) ^ (lr & 7)) * 8]);
#pragma unroll
      for (int mt = 0; mt < 4; mt++)
#pragma unroll
        for (int nt = 0; nt < 4; nt++)
          acc[mt][nt] = MFMA16(a[mt], b[nt], acc[mt][nt]);
    }
    __syncthreads();
  }

  int which = bn / 6;          // 0=q 1=k 2=v  (768 = 6*128 -> aligned)
  int hbase = (bn % 6) * 128;
#pragma unroll
  for (int mt = 0; mt < 4; mt++)
#pragma unroll
    for (int nt = 0; nt < 4; nt++) {
      int colL = wn * 64 + nt * 16 + lr;
      float bi = bias[bn * 128 + colL];
      int hcol = hbase + colL;
      int h = hcol >> 6, dcol = hcol & 63;
#pragma unroll
      for (int i = 0; i < 4; i++) {
        int m = bm * 128 + wm * 64 + mt * 16 + lg * 4 + i;
        if (m < MM) {
          float val = acc[mt][nt][i] + bi;
          int b = m / NN, n = m - b * NN;
          size_t bh = (size_t)b * HH + h;
          if (which == 0)
            q[(bh * NPQ + n) * DH + dcol] = (f16)(val * QSCALE);
          else if (which == 1)
            karr[(bh * NP + n) * DH + dcol] = (f16)val;
          else
            vT[(bh * DH + dcol) * NP + n] = (f16)val;
        }
      }
    }
}

// ---------------------------------------------------------------------------
// K2: fused attention, 64 q-rows per WAVE (4 row-groups in register): each
// loaded K fragment pair feeds FOUR score MFMAs, each V fragment feeds four
// PV MFMAs -> per-row global load instructions halve again vs R14 (which
// proved load-instruction throughput is the binding resource: -38us).
// LDS ~80KB -> 2 blocks/CU. Grid: 1920, block 256 (4 waves).
// ---------------------------------------------------------------------------
__global__ __launch_bounds__(256) void attn_kernel(
    const f16* __restrict__ q, const f16* __restrict__ karr,
    const f16* __restrict__ vT, float* __restrict__ weights,
    f16* __restrict__ ctx) {
  __shared__ f16 P[4][16][616];  // unnormalized exp2(scores), [rg][row][col]
  __shared__ float redS[4][4][16];     // [rg][wave][row]
  __shared__ float invA_lds[4][16];
  __shared__ float invB_lds[4][16];

  int bid = blockIdx.x;
  int wgid = (bid & 7) * (NWG64 / 8) + (bid >> 3);  // bijective XCD swizzle
  int bh = wgid / NQT, qt = wgid - bh * NQT;

  int tid = threadIdx.x, wid = tid >> 6, lane = tid & 63;
  int lr = lane & 15, lg = lane >> 4;
  int qbase = qt * 64;

  // q fragments for FOUR 16-row groups (rows qbase + g*16 + lr)
  const f16* qr0 = q + ((size_t)bh * NPQ + qbase + lr) * DH;
  f16x8 a[4][2];
#pragma unroll
  for (int g = 0; g < 4; g++) {
    a[g][0] = *reinterpret_cast<const f16x8*>(&qr0[g * 16 * DH + lg * 8]);
    a[g][1] = *reinterpret_cast<const f16x8*>(&qr0[g * 16 * DH + 32 + lg * 8]);
  }

  const f16* kb = karr + (size_t)bh * NP * DH;
  float psA[4] = {0.f, 0.f, 0.f, 0.f}, psB[4] = {0.f, 0.f, 0.f, 0.f};
#pragma unroll
  for (int t = 0; t < TPW; t++) {
    int ct = wid * TPW + t;
    int ctc = ct < NT ? ct : NT - 1;  // clamped (safe) address
    bool live = ct < NT;
    const f16* krp = &kb[(size_t)(ctc * 16 + lr) * DH];
    f16x8 b0 = *reinterpret_cast<const f16x8*>(&krp[lg * 8]);
    f16x8 b1 = *reinterpret_cast<const f16x8*>(&krp[32 + lg * 8]);
#pragma unroll
    for (int g = 0; g < 4; g++) {
      f32x4 acc = {};
      acc = MFMA16(b0, a[g][0], acc);   // S^T: row = k-col, col = q-row
      acc = MFMA16(b1, a[g][1], acc);
      f16x4 pk;
#pragma unroll
      for (int i = 0; i < 4; i++) {
        int col = ct * 16 + lg * 4 + i;   // k column
        bool inA = col < NCLS;
        bool valid = live && (col < NN);
        float e = valid ? __builtin_amdgcn_exp2f(acc[i]) : 0.f;
        if (inA) psA[g] += e; else psB[g] += e;
        pk[i] = (f16)e;
      }
      if (live)
        *reinterpret_cast<f16x4*>(&P[g][lr][ct * 16 + lg * 4]) = pk;
    }
  }
  // reduce across the 4 lanes sharing q-row lr (lanes lr, lr+16, lr+32, lr+48)
#pragma unroll
  for (int g = 0; g < 4; g++) {
    psA[g] += __shfl_xor(psA[g], 16); psA[g] += __shfl_xor(psA[g], 32);
    psB[g] += __shfl_xor(psB[g], 16); psB[g] += __shfl_xor(psB[g], 32);
  }
  if (lane < 16) {
#pragma unroll
    for (int g = 0; g < 4; g++) redS[g][wid][lr] = psB[g];
    if (wid == 0)  // cls cols live entirely in wave 0
#pragma unroll
      for (int g = 0; g < 4; g++) invA_lds[g][lr] = 1.0f / psA[g];
  }
  __syncthreads();
  if (wid == 2 && lane < 16)
#pragma unroll
    for (int g = 0; g < 4; g++)
      invB_lds[g][lr] = 1.0f / (redS[g][0][lr] + redS[g][1][lr] +
                                redS[g][2][lr] + redS[g][3][lr]);
  __syncthreads();

  // weights write: static mapping, each thread: one row per row-group
  {
    int row = tid >> 4, sub = tid & 15;
#pragma unroll
    for (int g = 0; g < 4; g++) {
      int grow = qbase + g * 16 + row;
      if (grow < NN) {
        float iA = invA_lds[g][row];
        float iB = invB_lds[g][row];
        const f16* prow = &P[g][row][0];
        float* wrow = weights + ((size_t)bh * NN + grow) * NN;
#pragma unroll
        for (int k2 = 0; k2 < 10; k2++) {
          int f4 = sub + 16 * k2;
          if (f4 < NN / 4) {
            float inv = (f4 < 5) ? iA : iB;
            f16x4 pv = *reinterpret_cast<const f16x4*>(&prow[f4 * 4]);
            float4 o4 = {(float)pv[0] * inv, (float)pv[1] * inv,
                         (float)pv[2] * inv, (float)pv[3] * inv};
            *reinterpret_cast<float4*>(&wrow[f4 * 4]) = o4;
          }
        }
      }
    }
  }

  // PV (swapped): D[d][q]; each V fragment feeds FOUR row-groups' MFMAs.
  const f16* vrow = vT + (size_t)bh * DH * NP + (size_t)(wid * 16 + lr) * NP;
  f32x4 oA[4] = {}, oB[4] = {};
  {
    f16x8 bv = *reinterpret_cast<const f16x8*>(&vrow[lg * 8]);
#pragma unroll
    for (int g = 0; g < 4; g++) {
      f16x8 pa = *reinterpret_cast<const f16x8*>(&P[g][lr][lg * 8]);
      f16x8 paA = pa, paB = pa;
#pragma unroll
      for (int j = 0; j < 8; j++) {
        if (lg * 8 + j < NCLS) paB[j] = (f16)0.f;
        else paA[j] = (f16)0.f;
      }
      oA[g] = MFMA16(bv, paA, oA[g]);
      oB[g] = MFMA16(bv, paB, oB[g]);
    }
  }
#pragma unroll
  for (int j = 1; j < 19; j++) {
    f16x8 bv = *reinterpret_cast<const f16x8*>(&vrow[j * 32 + lg * 8]);
#pragma unroll
    for (int g = 0; g < 4; g++) {
      f16x8 pa = *reinterpret_cast<const f16x8*>(&P[g][lr][j * 32 + lg * 8]);
      oB[g] = MFMA16(bv, pa, oB[g]);
    }
  }

  // epilogue: lane holds D[d = wid*16 + lg*4 + i][q = lr] for all 4 groups
  int b = bh / HH, h = bh - b * HH;
#pragma unroll
  for (int g = 0; g < 4; g++) {
    int qrow = qbase + g * 16 + lr;
    if (qrow < NN) {
      float iA = invA_lds[g][lr], iB = invB_lds[g][lr];
      f16x4 o4;
#pragma unroll
      for (int i = 0; i < 4; i++) o4[i] = (f16)(oA[g][i] * iA + oB[g][i] * iB);
      *reinterpret_cast<f16x4*>(
          &ctx[((size_t)b * NN + qrow) * CC + h * DH + wid * 16 + lg * 4]) = o4;
    }
  }
}

// ---------------------------------------------------------------------------
// K3: proj GEMM, 128x128x64 tiles, global_load_lds + XOR swizzle.
// ---------------------------------------------------------------------------
__global__ __launch_bounds__(256) void proj_gemm(
    const f16* __restrict__ ctx, const f16* __restrict__ wT,
    const float* __restrict__ bias, float* __restrict__ out) {
  __shared__ f16 As[128 * 64];
  __shared__ f16 Bs[128 * 64];
  int bn = blockIdx.x, bm = blockIdx.y;
  int tid = threadIdx.x;
  int wid = tid >> 6, lane = tid & 63;
  int wm = wid >> 1, wn = wid & 1;
  int lr = lane & 15, lg = lane >> 4;
  int srcChunk = (lane & 7) ^ (lane >> 3);

  const f16* gA = &ctx[((size_t)bm * 128 + (lane >> 3)) * CC + srcChunk * 8];
  const f16* gB = &wT[((size_t)bn * 128 + (lane >> 3)) * CC + srcChunk * 8];

  f32x4 acc[4][4] = {};
  for (int k0 = 0; k0 < CC; k0 += 64) {
#pragma unroll
    for (int j = 0; j < 4; j++) {
      int r0 = (wid * 4 + j) * 8;
      gload16(gA + (size_t)r0 * CC + k0, &As[r0 * 64]);
      gload16(gB + (size_t)r0 * CC + k0, &Bs[r0 * 64]);
    }
    __syncthreads();
#pragma unroll
    for (int ks = 0; ks < 2; ks++) {
      f16x8 a[4], b[4];
#pragma unroll
      for (int mt = 0; mt < 4; mt++)
        a[mt] = *reinterpret_cast<const f16x8*>(
            &As[(wm * 64 + mt * 16 + lr) * 64 + ((ks * 4 + lg) ^ (lr & 7)) * 8]);
#pragma unroll
      for (int nt = 0; nt < 4; nt++)
        b[nt] = *reinterpret_cast<const f16x8*>(
            &Bs[(wn * 64 + nt * 16 + lr) * 64 + ((ks * 4 + lg) ^ (lr & 7)) * 8]);
#pragma unroll
      for (int mt = 0; mt < 4; mt++)
#pragma unroll
        for (int nt = 0; nt < 4; nt++)
          acc[mt][nt] = MFMA16(a[mt], b[nt], acc[mt][nt]);
    }
    __syncthreads();
  }
#pragma unroll
  for (int mt = 0; mt < 4; mt++)
#pragma unroll
    for (int nt = 0; nt < 4; nt++) {
      int colL = wn * 64 + nt * 16 + lr;
      float bi = bias[bn * 128 + colL];
#pragma unroll
      for (int i = 0; i < 4; i++) {
        int m = bm * 128 + wm * 64 + mt * 16 + lg * 4 + i;
        if (m < MM)
          out[(size_t)m * CC + bn * 128 + colL] = acc[mt][nt][i] + bi;
      }
    }
}

// ---------------------------------------------------------------------------
extern "C" void kernel_launch(void* const* d_in, const int* in_sizes, int n_in,
                              void* d_out, int out_size, void* d_ws,
                              size_t ws_size, hipStream_t stream) {
  const float* x      = (const float*)d_in[0];
  const float* w_qkv  = (const float*)d_in[1];
  const float* b_qkv  = (const float*)d_in[2];
  const float* w_proj = (const float*)d_in[3];
  const float* b_proj = (const float*)d_in[4];

  float* out     = (float*)d_out;
  float* weights = out + (size_t)MM * CC;

  f16* p      = (f16*)d_ws;
  f16* wqkvT  = p;  p += (size_t)K3C * CC;
  f16* wprojT = p;  p += (size_t)CC * CC;
  f16* x16    = p;  p += (size_t)MMP * CC;
  f16* qb     = p;  p += (size_t)BH * NPQ * DH;
  f16* kb     = p;  p += (size_t)BH * NP * DH;
  f16* vT     = p;  p += (size_t)BH * DH * NP;
  f16* ctx    = p;  p += (size_t)MMP * CC;

  prep<<<1728 + 576 + 3600 + 192, 256, 0, stream>>>(w_qkv, w_proj, x, wqkvT,
                                                    wprojT, x16, qb, kb, vT);
  qkv_gemm<<<dim3(K3C / 128, MMP / 128), 256, 0, stream>>>(x16, wqkvT, b_qkv,
                                                           qb, kb, vT);
  attn_kernel<<<NWG64, 256, 0, stream>>>(qb, kb, vT, weights, ctx);
  proj_gemm<<<dim3(CC / 128, MMP / 128), 256, 0, stream>>>(ctx, wprojT, b_proj,
                                                           out);
}

// Round 16
// 205.350 us; speedup vs baseline: 3.7513x; 1.0506x over previous
//
#include <hip/hip_runtime.h>
#include <hip/hip_fp16.h>
#include <stdint.h>

typedef _Float16 f16;
typedef _Float16 f16x8 __attribute__((ext_vector_type(8)));
typedef _Float16 f16x4 __attribute__((ext_vector_type(4)));
typedef float f32x4 __attribute__((ext_vector_type(4)));

#define MFMA16(a, b, c) __builtin_amdgcn_mfma_f32_16x16x32_f16(a, b, c, 0, 0, 0)

constexpr int BB   = 16;
constexpr int NN   = 596;
constexpr int CC   = 768;
constexpr int HH   = 12;
constexpr int DH   = 64;
constexpr int NCLS = 20;
constexpr int BH   = BB * HH;   // 192
constexpr int NP   = 608;       // k/v seq padded to multiple of 32
constexpr int NPQ  = 640;       // q seq padded to multiple of 64
constexpr int MM   = BB * NN;   // 9536
constexpr int MMP  = 9600;      // M padded to multiple of 128
constexpr int K3C  = 3 * CC;    // 2304
constexpr int NT   = NP / 16;   // 38 col tiles
constexpr int TPW  = 10;        // col tiles per wave (4 waves: 10/10/10/8)
constexpr int NQT  = NPQ / 64;  // 10 q-tiles of 64 rows
constexpr int NWG64 = NQT * BH; // 1920 = 8 * 240

// q pre-scale: Dh^-0.5 * log2(e), so attn uses exp2 (raw v_exp_f32)
#define QSCALE 0.18033688011112042f

// direct global->LDS DMA, 16B per lane, LDS dest = wave-uniform base + lane*16
__device__ __forceinline__ void gload16(const f16* g, f16* l) {
  __builtin_amdgcn_global_load_lds(
      (const __attribute__((address_space(1))) void*)g,
      (__attribute__((address_space(3))) void*)l, 16, 0, 0);
}

// ---------------------------------------------------------------------------
// K0: fused prep: wqkv^T, wproj^T (fp16), x->fp16 (padded), zero q/k/vT pads.
// ---------------------------------------------------------------------------
__global__ __launch_bounds__(256) void prep(
    const float* __restrict__ w_qkv, const float* __restrict__ w_proj,
    const float* __restrict__ x, f16* __restrict__ wqkvT,
    f16* __restrict__ wprojT, f16* __restrict__ x16, f16* __restrict__ q,
    f16* __restrict__ k, f16* __restrict__ vT) {
  __shared__ float t[32][33];
  int b = blockIdx.x;
  if (b < 1728 + 576) {  // transposes
    const float* src = b < 1728 ? w_qkv : w_proj;
    f16* dst = b < 1728 ? wqkvT : wprojT;
    int Ccols = b < 1728 ? K3C : CC;
    int bi = b < 1728 ? b : b - 1728;
    int nbx = Ccols / 32;
    int tile_c = (bi % nbx) * 32, tile_r = (bi / nbx) * 32;
    int tr = threadIdx.x & 31, tg = threadIdx.x >> 5;
#pragma unroll
    for (int i = 0; i < 4; i++)
      t[tg + i * 8][tr] = src[(size_t)(tile_r + tg + i * 8) * Ccols + tile_c + tr];
    __syncthreads();
#pragma unroll
    for (int i = 0; i < 4; i++)
      dst[(size_t)(tile_c + tg + i * 8) * CC + tile_r + tr] =
          (f16)t[tr][tg + i * 8];
    return;
  }
  b -= 1728 + 576;
  if (b < 3600) {  // convert x
    size_t idx = ((size_t)b * 256 + threadIdx.x) * 8;
    f16x8 h;
    if (idx < (size_t)MM * CC) {
      float4 v0 = *reinterpret_cast<const float4*>(&x[idx]);
      float4 v1 = *reinterpret_cast<const float4*>(&x[idx + 4]);
      h[0] = (f16)v0.x; h[1] = (f16)v0.y; h[2] = (f16)v0.z; h[3] = (f16)v0.w;
      h[4] = (f16)v1.x; h[5] = (f16)v1.y; h[6] = (f16)v1.z; h[7] = (f16)v1.w;
    } else {
      h = (f16x8){0, 0, 0, 0, 0, 0, 0, 0};
    }
    *reinterpret_cast<f16x8*>(&x16[idx]) = h;
    return;
  }
  b -= 3600;  // zero pads, b = bh
  int tid = threadIdx.x;
  for (int i = tid; i < (NPQ - NN) * DH; i += 256) {  // q: 44 pad rows
    int n = NN + (i >> 6), d = i & 63;
    q[((size_t)b * NPQ + n) * DH + d] = (f16)0.f;
  }
  for (int i = tid; i < 12 * DH; i += 256) {          // k: 12 pad rows
    int n = NN + (i >> 6), d = i & 63;
    k[((size_t)b * NP + n) * DH + d] = (f16)0.f;
  }
  for (int i = tid; i < DH * 12; i += 256) {          // vT: 12 pad cols
    int d = i / 12, n = NN + (i % 12);
    vT[((size_t)b * DH + d) * NP + n] = (f16)0.f;
  }
}

// ---------------------------------------------------------------------------
// K1: QKV GEMM, 128x128x64 tiles, global_load_lds staging + XOR swizzle.
// NEW: q/k epilogue stages the 128x128 f16 tile in LDS (reusing the staging
// buffer, XOR-swizzled cols) and streams it out as 8x16B coalesced stores
// per thread instead of 64x2B scatter stores. v keeps the scalar path
// (transposed target crosses batch boundaries within 16B chunks).
// ---------------------------------------------------------------------------
__global__ __launch_bounds__(256) void qkv_gemm(
    const f16* __restrict__ x16, const f16* __restrict__ wT,
    const float* __restrict__ bias, f16* __restrict__ q,
    f16* __restrict__ karr, f16* __restrict__ vT) {
  __shared__ f16 sbuf[128 * 128];      // 32KB: staging (A|B) then C tile
  f16* As = sbuf;                      // [128][64]
  f16* Bs = sbuf + 128 * 64;           // [128][64]
  int bn = blockIdx.x, bm = blockIdx.y;
  int tid = threadIdx.x;
  int wid = tid >> 6, lane = tid & 63;
  int wm = wid >> 1, wn = wid & 1;
  int lr = lane & 15, lg = lane >> 4;
  int srcChunk = (lane & 7) ^ (lane >> 3);

  const f16* gA = &x16[((size_t)bm * 128 + (lane >> 3)) * CC + srcChunk * 8];
  const f16* gB = &wT[((size_t)bn * 128 + (lane >> 3)) * CC + srcChunk * 8];

  f32x4 acc[4][4] = {};
  for (int k0 = 0; k0 < CC; k0 += 64) {
#pragma unroll
    for (int j = 0; j < 4; j++) {
      int r0 = (wid * 4 + j) * 8;
      gload16(gA + (size_t)r0 * CC + k0, &As[r0 * 64]);
      gload16(gB + (size_t)r0 * CC + k0, &Bs[r0 * 64]);
    }
    __syncthreads();
#pragma unroll
    for (int ks = 0; ks < 2; ks++) {
      f16x8 a[4], b[4];
#pragma unroll
      for (int mt = 0; mt < 4; mt++)
        a[mt] = *reinterpret_cast<const f16x8*>(
            &As[(wm * 64 + mt * 16 + lr) * 64 + ((ks * 4 + lg) ^ (lr & 7)) * 8]);
#pragma unroll
      for (int nt = 0; nt < 4; nt++)
        b[nt] = *reinterpret_cast<const f16x8*>(
            &Bs[(wn * 64 + nt * 16 + lr) * 64 + ((ks * 4 + lg) ^ (lr & 7)) * 8]);
#pragma unroll
      for (int mt = 0; mt < 4; mt++)
#pragma unroll
        for (int nt = 0; nt < 4; nt++)
          acc[mt][nt] = MFMA16(a[mt], b[nt], acc[mt][nt]);
    }
    __syncthreads();
  }

  int which = bn / 6;          // 0=q 1=k 2=v  (768 = 6*128 -> aligned)
  int hbase = (bn % 6) * 128;

  if (which < 2) {
    // ---- coalesced path: acc -> LDS (f16, swizzled) -> 16B stores ----
    float sc = (which == 0) ? QSCALE : 1.0f;
#pragma unroll
    for (int mt = 0; mt < 4; mt++)
#pragma unroll
      for (int nt = 0; nt < 4; nt++) {
        int colL = wn * 64 + nt * 16 + lr;
        float bi = bias[bn * 128 + colL];
#pragma unroll
        for (int i = 0; i < 4; i++) {
          int row = wm * 64 + mt * 16 + lg * 4 + i;
          int c = colL ^ ((row & 7) << 3);  // swizzle col bits 3..5
          sbuf[row * 128 + c] = (f16)((acc[mt][nt][i] + bi) * sc);
        }
      }
    __syncthreads();
#pragma unroll
    for (int p = 0; p < 8; p++) {
      int row = p * 16 + (tid >> 4);
      int c8 = tid & 15;
      int m = bm * 128 + row;
      if (m < MM) {
        f16x8 v = *reinterpret_cast<const f16x8*>(
            &sbuf[row * 128 + ((c8 ^ (row & 7)) * 8)]);
        int hcol = hbase + c8 * 8;
        int h = hcol >> 6, dc = hcol & 63;
        int b = m / NN, n = m - b * NN;
        size_t bh = (size_t)b * HH + h;
        f16* dst = (which == 0) ? &q[(bh * NPQ + n) * DH + dc]
                                : &karr[(bh * NP + n) * DH + dc];
        *reinterpret_cast<f16x8*>(dst) = v;
      }
    }
  } else {
    // ---- v path: scalar scatter into vT (unchanged) ----
#pragma unroll
    for (int mt = 0; mt < 4; mt++)
#pragma unroll
      for (int nt = 0; nt < 4; nt++) {
        int colL = wn * 64 + nt * 16 + lr;
        float bi = bias[bn * 128 + colL];
        int hcol = hbase + colL;
        int h = hcol >> 6, dcol = hcol & 63;
#pragma unroll
        for (int i = 0; i < 4; i++) {
          int m = bm * 128 + wm * 64 + mt * 16 + lg * 4 + i;
          if (m < MM) {
            float val = acc[mt][nt][i] + bi;
            int b = m / NN, n = m - b * NN;
            size_t bh = (size_t)b * HH + h;
            vT[(bh * DH + dcol) * NP + n] = (f16)val;
          }
        }
      }
  }
}

// ---------------------------------------------------------------------------
// K2: fused attention, 64 q-rows per WAVE (4 row-groups in register), from
// R15 (equal to R14 within noise). Swapped-operand MFMA, exp2 domain,
// deferred normalization, coalesced weights write.
// Grid: 1920, block 256 (4 waves).
// ---------------------------------------------------------------------------
__global__ __launch_bounds__(256) void attn_kernel(
    const f16* __restrict__ q, const f16* __restrict__ karr,
    const f16* __restrict__ vT, float* __restrict__ weights,
    f16* __restrict__ ctx) {
  __shared__ f16 P[4][16][616];  // unnormalized exp2(scores), [rg][row][col]
  __shared__ float redS[4][4][16];     // [rg][wave][row]
  __shared__ float invA_lds[4][16];
  __shared__ float invB_lds[4][16];

  int bid = blockIdx.x;
  int wgid = (bid & 7) * (NWG64 / 8) + (bid >> 3);  // bijective XCD swizzle
  int bh = wgid / NQT, qt = wgid - bh * NQT;

  int tid = threadIdx.x, wid = tid >> 6, lane = tid & 63;
  int lr = lane & 15, lg = lane >> 4;
  int qbase = qt * 64;

  // q fragments for FOUR 16-row groups (rows qbase + g*16 + lr)
  const f16* qr0 = q + ((size_t)bh * NPQ + qbase + lr) * DH;
  f16x8 a[4][2];
#pragma unroll
  for (int g = 0; g < 4; g++) {
    a[g][0] = *reinterpret_cast<const f16x8*>(&qr0[g * 16 * DH + lg * 8]);
    a[g][1] = *reinterpret_cast<const f16x8*>(&qr0[g * 16 * DH + 32 + lg * 8]);
  }

  const f16* kb = karr + (size_t)bh * NP * DH;
  float psA[4] = {0.f, 0.f, 0.f, 0.f}, psB[4] = {0.f, 0.f, 0.f, 0.f};
#pragma unroll
  for (int t = 0; t < TPW; t++) {
    int ct = wid * TPW + t;
    int ctc = ct < NT ? ct : NT - 1;  // clamped (safe) address
    bool live = ct < NT;
    const f16* krp = &kb[(size_t)(ctc * 16 + lr) * DH];
    f16x8 b0 = *reinterpret_cast<const f16x8*>(&krp[lg * 8]);
    f16x8 b1 = *reinterpret_cast<const f16x8*>(&krp[32 + lg * 8]);
#pragma unroll
    for (int g = 0; g < 4; g++) {
      f32x4 acc = {};
      acc = MFMA16(b0, a[g][0], acc);   // S^T: row = k-col, col = q-row
      acc = MFMA16(b1, a[g][1], acc);
      f16x4 pk;
#pragma unroll
      for (int i = 0; i < 4; i++) {
        int col = ct * 16 + lg * 4 + i;   // k column
        bool inA = col < NCLS;
        bool valid = live && (col < NN);
        float e = valid ? __builtin_amdgcn_exp2f(acc[i]) : 0.f;
        if (inA) psA[g] += e; else psB[g] += e;
        pk[i] = (f16)e;
      }
      if (live)
        *reinterpret_cast<f16x4*>(&P[g][lr][ct * 16 + lg * 4]) = pk;
    }
  }
  // reduce across the 4 lanes sharing q-row lr (lanes lr, lr+16, lr+32, lr+48)
#pragma unroll
  for (int g = 0; g < 4; g++) {
    psA[g] += __shfl_xor(psA[g], 16); psA[g] += __shfl_xor(psA[g], 32);
    psB[g] += __shfl_xor(psB[g], 16); psB[g] += __shfl_xor(psB[g], 32);
  }
  if (lane < 16) {
#pragma unroll
    for (int g = 0; g < 4; g++) redS[g][wid][lr] = psB[g];
    if (wid == 0)  // cls cols live entirely in wave 0
#pragma unroll
      for (int g = 0; g < 4; g++) invA_lds[g][lr] = 1.0f / psA[g];
  }
  __syncthreads();
  if (wid == 2 && lane < 16)
#pragma unroll
    for (int g = 0; g < 4; g++)
      invB_lds[g][lr] = 1.0f / (redS[g][0][lr] + redS[g][1][lr] +
                                redS[g][2][lr] + redS[g][3][lr]);
  __syncthreads();

  // weights write: static mapping, each thread: one row per row-group
  {
    int row = tid >> 4, sub = tid & 15;
#pragma unroll
    for (int g = 0; g < 4; g++) {
      int grow = qbase + g * 16 + row;
      if (grow < NN) {
        float iA = invA_lds[g][row];
        float iB = invB_lds[g][row];
        const f16* prow = &P[g][row][0];
        float* wrow = weights + ((size_t)bh * NN + grow) * NN;
#pragma unroll
        for (int k2 = 0; k2 < 10; k2++) {
          int f4 = sub + 16 * k2;
          if (f4 < NN / 4) {
            float inv = (f4 < 5) ? iA : iB;
            f16x4 pv = *reinterpret_cast<const f16x4*>(&prow[f4 * 4]);
            float4 o4 = {(float)pv[0] * inv, (float)pv[1] * inv,
                         (float)pv[2] * inv, (float)pv[3] * inv};
            *reinterpret_cast<float4*>(&wrow[f4 * 4]) = o4;
          }
        }
      }
    }
  }

  // PV (swapped): D[d][q]; each V fragment feeds FOUR row-groups' MFMAs.
  const f16* vrow = vT + (size_t)bh * DH * NP + (size_t)(wid * 16 + lr) * NP;
  f32x4 oA[4] = {}, oB[4] = {};
  {
    f16x8 bv = *reinterpret_cast<const f16x8*>(&vrow[lg * 8]);
#pragma unroll
    for (int g = 0; g < 4; g++) {
      f16x8 pa = *reinterpret_cast<const f16x8*>(&P[g][lr][lg * 8]);
      f16x8 paA = pa, paB = pa;
#pragma unroll
      for (int j = 0; j < 8; j++) {
        if (lg * 8 + j < NCLS) paB[j] = (f16)0.f;
        else paA[j] = (f16)0.f;
      }
      oA[g] = MFMA16(bv, paA, oA[g]);
      oB[g] = MFMA16(bv, paB, oB[g]);
    }
  }
#pragma unroll
  for (int j = 1; j < 19; j++) {
    f16x8 bv = *reinterpret_cast<const f16x8*>(&vrow[j * 32 + lg * 8]);
#pragma unroll
    for (int g = 0; g < 4; g++) {
      f16x8 pa = *reinterpret_cast<const f16x8*>(&P[g][lr][j * 32 + lg * 8]);
      oB[g] = MFMA16(bv, pa, oB[g]);
    }
  }

  // epilogue: lane holds D[d = wid*16 + lg*4 + i][q = lr] for all 4 groups
  int b = bh / HH, h = bh - b * HH;
#pragma unroll
  for (int g = 0; g < 4; g++) {
    int qrow = qbase + g * 16 + lr;
    if (qrow < NN) {
      float iA = invA_lds[g][lr], iB = invB_lds[g][lr];
      f16x4 o4;
#pragma unroll
      for (int i = 0; i < 4; i++) o4[i] = (f16)(oA[g][i] * iA + oB[g][i] * iB);
      *reinterpret_cast<f16x4*>(
          &ctx[((size_t)b * NN + qrow) * CC + h * DH + wid * 16 + lg * 4]) = o4;
    }
  }
}

// ---------------------------------------------------------------------------
// K3: proj GEMM, 128x128x64 tiles, global_load_lds + XOR swizzle.
// ---------------------------------------------------------------------------
__global__ __launch_bounds__(256) void proj_gemm(
    const f16* __restrict__ ctx, const f16* __restrict__ wT,
    const float* __restrict__ bias, float* __restrict__ out) {
  __shared__ f16 As[128 * 64];
  __shared__ f16 Bs[128 * 64];
  int bn = blockIdx.x, bm = blockIdx.y;
  int tid = threadIdx.x;
  int wid = tid >> 6, lane = tid & 63;
  int wm = wid >> 1, wn = wid & 1;
  int lr = lane & 15, lg = lane >> 4;
  int srcChunk = (lane & 7) ^ (lane >> 3);

  const f16* gA = &ctx[((size_t)bm * 128 + (lane >> 3)) * CC + srcChunk * 8];
  const f16* gB = &wT[((size_t)bn * 128 + (lane >> 3)) * CC + srcChunk * 8];

  f32x4 acc[4][4] = {};
  for (int k0 = 0; k0 < CC; k0 += 64) {
#pragma unroll
    for (int j = 0; j < 4; j++) {
      int r0 = (wid * 4 + j) * 8;
      gload16(gA + (size_t)r0 * CC + k0, &As[r0 * 64]);
      gload16(gB + (size_t)r0 * CC + k0, &Bs[r0 * 64]);
    }
    __syncthreads();
#pragma unroll
    for (int ks = 0; ks < 2; ks++) {
      f16x8 a[4], b[4];
#pragma unroll
      for (int mt = 0; mt < 4; mt++)
        a[mt] = *reinterpret_cast<const f16x8*>(
            &As[(wm * 64 + mt * 16 + lr) * 64 + ((ks * 4 + lg) ^ (lr & 7)) * 8]);
#pragma unroll
      for (int nt = 0; nt < 4; nt++)
        b[nt] = *reinterpret_cast<const f16x8*>(
            &Bs[(wn * 64 + nt * 16 + lr) * 64 + ((ks * 4 + lg) ^ (lr & 7)) * 8]);
#pragma unroll
      for (int mt = 0; mt < 4; mt++)
#pragma unroll
        for (int nt = 0; nt < 4; nt++)
          acc[mt][nt] = MFMA16(a[mt], b[nt], acc[mt][nt]);
    }
    __syncthreads();
  }
#pragma unroll
  for (int mt = 0; mt < 4; mt++)
#pragma unroll
    for (int nt = 0; nt < 4; nt++) {
      int colL = wn * 64 + nt * 16 + lr;
      float bi = bias[bn * 128 + colL];
#pragma unroll
      for (int i = 0; i < 4; i++) {
        int m = bm * 128 + wm * 64 + mt * 16 + lg * 4 + i;
        if (m < MM)
          out[(size_t)m * CC + bn * 128 + colL] = acc[mt][nt][i] + bi;
      }
    }
}

// ---------------------------------------------------------------------------
extern "C" void kernel_launch(void* const* d_in, const int* in_sizes, int n_in,
                              void* d_out, int out_size, void* d_ws,
                              size_t ws_size, hipStream_t stream) {
  const float* x      = (const float*)d_in[0];
  const float* w_qkv  = (const float*)d_in[1];
  const float* b_qkv  = (const float*)d_in[2];
  const float* w_proj = (const float*)d_in[3];
  const float* b_proj = (const float*)d_in[4];

  float* out     = (float*)d_out;
  float* weights = out + (size_t)MM * CC;

  f16* p      = (f16*)d_ws;
  f16* wqkvT  = p;  p += (size_t)K3C * CC;
  f16* wprojT = p;  p += (size_t)CC * CC;
  f16* x16    = p;  p += (size_t)MMP * CC;
  f16* qb     = p;  p += (size_t)BH * NPQ * DH;
  f16* kb     = p;  p += (size_t)BH * NP * DH;
  f16* vT     = p;  p += (size_t)BH * DH * NP;
  f16* ctx    = p;  p += (size_t)MMP * CC;

  prep<<<1728 + 576 + 3600 + 192, 256, 0, stream>>>(w_qkv, w_proj, x, wqkvT,
                                                    wprojT, x16, qb, kb, vT);
  qkv_gemm<<<dim3(K3C / 128, MMP / 128), 256, 0, stream>>>(x16, wqkvT, b_qkv,
                                                           qb, kb, vT);
  attn_kernel<<<NWG64, 256, 0, stream>>>(qb, kb, vT, weights, ctx);
  proj_gemm<<<dim3(CC / 128, MMP / 128), 256, 0, stream>>>(ctx, wprojT, b_proj,
                                                           out);
}

// Round 17
// 183.389 us; speedup vs baseline: 4.2005x; 1.1197x over previous
//
#include <hip/hip_runtime.h>
#include <hip/hip_fp16.h>
#include <stdint.h>

typedef _Float16 f16;
typedef _Float16 f16x8 __attribute__((ext_vector_type(8)));
typedef _Float16 f16x4 __attribute__((ext_vector_type(4)));
typedef float f32x4 __attribute__((ext_vector_type(4)));

#define MFMA16(a, b, c) __builtin_amdgcn_mfma_f32_16x16x32_f16(a, b, c, 0, 0, 0)

constexpr int BB   = 16;
constexpr int NN   = 596;
constexpr int CC   = 768;
constexpr int HH   = 12;
constexpr int DH   = 64;
constexpr int NCLS = 20;
constexpr int BH   = BB * HH;   // 192
constexpr int NP   = 608;       // k/v seq padded to multiple of 32
constexpr int NPQ  = 640;       // q seq padded to multiple of 64
constexpr int MM   = BB * NN;   // 9536
constexpr int MMP  = 9600;      // M padded to multiple of 128
constexpr int K3C  = 3 * CC;    // 2304
constexpr int NT   = NP / 16;   // 38 col tiles
constexpr int TPW  = 10;        // col tiles per wave (4 waves: 10/10/10/8)
constexpr int NQT  = NPQ / 64;  // 10 q-tiles of 64 rows
constexpr int NWG64 = NQT * BH; // 1920 = 8 * 240

// q pre-scale: Dh^-0.5 * log2(e), so attn uses exp2 (raw v_exp_f32)
#define QSCALE 0.18033688011112042f

// direct global->LDS DMA, 16B per lane, LDS dest = wave-uniform base + lane*16
__device__ __forceinline__ void gload16(const f16* g, f16* l) {
  __builtin_amdgcn_global_load_lds(
      (const __attribute__((address_space(1))) void*)g,
      (__attribute__((address_space(3))) void*)l, 16, 0, 0);
}

// ---------------------------------------------------------------------------
// K0: fused prep: wqkv^T, wproj^T (fp16), x->fp16 (padded), zero q/k/vT pads.
// ---------------------------------------------------------------------------
__global__ __launch_bounds__(256) void prep(
    const float* __restrict__ w_qkv, const float* __restrict__ w_proj,
    const float* __restrict__ x, f16* __restrict__ wqkvT,
    f16* __restrict__ wprojT, f16* __restrict__ x16, f16* __restrict__ q,
    f16* __restrict__ k, f16* __restrict__ vT) {
  __shared__ float t[32][33];
  int b = blockIdx.x;
  if (b < 1728 + 576) {  // transposes
    const float* src = b < 1728 ? w_qkv : w_proj;
    f16* dst = b < 1728 ? wqkvT : wprojT;
    int Ccols = b < 1728 ? K3C : CC;
    int bi = b < 1728 ? b : b - 1728;
    int nbx = Ccols / 32;
    int tile_c = (bi % nbx) * 32, tile_r = (bi / nbx) * 32;
    int tr = threadIdx.x & 31, tg = threadIdx.x >> 5;
#pragma unroll
    for (int i = 0; i < 4; i++)
      t[tg + i * 8][tr] = src[(size_t)(tile_r + tg + i * 8) * Ccols + tile_c + tr];
    __syncthreads();
#pragma unroll
    for (int i = 0; i < 4; i++)
      dst[(size_t)(tile_c + tg + i * 8) * CC + tile_r + tr] =
          (f16)t[tr][tg + i * 8];
    return;
  }
  b -= 1728 + 576;
  if (b < 3600) {  // convert x
    size_t idx = ((size_t)b * 256 + threadIdx.x) * 8;
    f16x8 h;
    if (idx < (size_t)MM * CC) {
      float4 v0 = *reinterpret_cast<const float4*>(&x[idx]);
      float4 v1 = *reinterpret_cast<const float4*>(&x[idx + 4]);
      h[0] = (f16)v0.x; h[1] = (f16)v0.y; h[2] = (f16)v0.z; h[3] = (f16)v0.w;
      h[4] = (f16)v1.x; h[5] = (f16)v1.y; h[6] = (f16)v1.z; h[7] = (f16)v1.w;
    } else {
      h = (f16x8){0, 0, 0, 0, 0, 0, 0, 0};
    }
    *reinterpret_cast<f16x8*>(&x16[idx]) = h;
    return;
  }
  b -= 3600;  // zero pads, b = bh
  int tid = threadIdx.x;
  for (int i = tid; i < (NPQ - NN) * DH; i += 256) {  // q: 44 pad rows
    int n = NN + (i >> 6), d = i & 63;
    q[((size_t)b * NPQ + n) * DH + d] = (f16)0.f;
  }
  for (int i = tid; i < 12 * DH; i += 256) {          // k: 12 pad rows
    int n = NN + (i >> 6), d = i & 63;
    k[((size_t)b * NP + n) * DH + d] = (f16)0.f;
  }
  for (int i = tid; i < DH * 12; i += 256) {          // vT: 12 pad cols
    int d = i / 12, n = NN + (i % 12);
    vT[((size_t)b * DH + d) * NP + n] = (f16)0.f;
  }
}

// ---------------------------------------------------------------------------
// K1: QKV GEMM, 128x128x64 tiles, global_load_lds staging + XOR swizzle.
// q/k epilogue: LDS-staged, 16B coalesced stores (R16, proven -10us).
// v epilogue NEW: tile staged TRANSPOSED in LDS (pitch 132 -> bank-spread),
// written as 8B f16x4 chunks with consecutive lanes on consecutive n
// (596%4==0 -> chunks never cross batch boundaries, always 4-aligned).
// ---------------------------------------------------------------------------
__global__ __launch_bounds__(256) void qkv_gemm(
    const f16* __restrict__ x16, const f16* __restrict__ wT,
    const float* __restrict__ bias, f16* __restrict__ q,
    f16* __restrict__ karr, f16* __restrict__ vT) {
  __shared__ f16 sbuf[128 * 132];      // 33KB: staging (A|B) then C tile
  f16* As = sbuf;                      // [128][64]
  f16* Bs = sbuf + 128 * 64;           // [128][64]
  int bn = blockIdx.x, bm = blockIdx.y;
  int tid = threadIdx.x;
  int wid = tid >> 6, lane = tid & 63;
  int wm = wid >> 1, wn = wid & 1;
  int lr = lane & 15, lg = lane >> 4;
  int srcChunk = (lane & 7) ^ (lane >> 3);

  const f16* gA = &x16[((size_t)bm * 128 + (lane >> 3)) * CC + srcChunk * 8];
  const f16* gB = &wT[((size_t)bn * 128 + (lane >> 3)) * CC + srcChunk * 8];

  f32x4 acc[4][4] = {};
  for (int k0 = 0; k0 < CC; k0 += 64) {
#pragma unroll
    for (int j = 0; j < 4; j++) {
      int r0 = (wid * 4 + j) * 8;
      gload16(gA + (size_t)r0 * CC + k0, &As[r0 * 64]);
      gload16(gB + (size_t)r0 * CC + k0, &Bs[r0 * 64]);
    }
    __syncthreads();
#pragma unroll
    for (int ks = 0; ks < 2; ks++) {
      f16x8 a[4], b[4];
#pragma unroll
      for (int mt = 0; mt < 4; mt++)
        a[mt] = *reinterpret_cast<const f16x8*>(
            &As[(wm * 64 + mt * 16 + lr) * 64 + ((ks * 4 + lg) ^ (lr & 7)) * 8]);
#pragma unroll
      for (int nt = 0; nt < 4; nt++)
        b[nt] = *reinterpret_cast<const f16x8*>(
            &Bs[(wn * 64 + nt * 16 + lr) * 64 + ((ks * 4 + lg) ^ (lr & 7)) * 8]);
#pragma unroll
      for (int mt = 0; mt < 4; mt++)
#pragma unroll
        for (int nt = 0; nt < 4; nt++)
          acc[mt][nt] = MFMA16(a[mt], b[nt], acc[mt][nt]);
    }
    __syncthreads();
  }

  int which = bn / 6;          // 0=q 1=k 2=v  (768 = 6*128 -> aligned)
  int hbase = (bn % 6) * 128;

  if (which < 2) {
    // ---- coalesced q/k path: acc -> LDS (f16, swizzled) -> 16B stores ----
    float sc = (which == 0) ? QSCALE : 1.0f;
#pragma unroll
    for (int mt = 0; mt < 4; mt++)
#pragma unroll
      for (int nt = 0; nt < 4; nt++) {
        int colL = wn * 64 + nt * 16 + lr;
        float bi = bias[bn * 128 + colL];
#pragma unroll
        for (int i = 0; i < 4; i++) {
          int row = wm * 64 + mt * 16 + lg * 4 + i;
          int c = colL ^ ((row & 7) << 3);  // swizzle col bits 3..5
          sbuf[row * 128 + c] = (f16)((acc[mt][nt][i] + bi) * sc);
        }
      }
    __syncthreads();
#pragma unroll
    for (int p = 0; p < 8; p++) {
      int row = p * 16 + (tid >> 4);
      int c8 = tid & 15;
      int m = bm * 128 + row;
      if (m < MM) {
        f16x8 v = *reinterpret_cast<const f16x8*>(
            &sbuf[row * 128 + ((c8 ^ (row & 7)) * 8)]);
        int hcol = hbase + c8 * 8;
        int h = hcol >> 6, dc = hcol & 63;
        int b = m / NN, n = m - b * NN;
        size_t bh = (size_t)b * HH + h;
        f16* dst = (which == 0) ? &q[(bh * NPQ + n) * DH + dc]
                                : &karr[(bh * NP + n) * DH + dc];
        *reinterpret_cast<f16x8*>(dst) = v;
      }
    }
  } else {
    // ---- v path: stage TRANSPOSED (sbufT[col][row], pitch 132), then 8B
    // ---- chunks along n with consecutive lanes on consecutive n-chunks.
#pragma unroll
    for (int mt = 0; mt < 4; mt++)
#pragma unroll
      for (int nt = 0; nt < 4; nt++) {
        int colL = wn * 64 + nt * 16 + lr;
        float bi = bias[bn * 128 + colL];
#pragma unroll
        for (int i = 0; i < 4; i++) {
          int row = wm * 64 + mt * 16 + lg * 4 + i;
          sbuf[colL * 132 + row] = (f16)(acc[mt][nt][i] + bi);
        }
      }
    __syncthreads();
    int nchunk = tid & 31;   // 32 chunks of 4 rows (m)
    int cgrp = tid >> 5;     // 8 col groups
    int m0 = bm * 128 + nchunk * 4;
    if (m0 < MM) {           // 596%4==0: chunk never crosses batch boundary
      int b = m0 / NN, n = m0 - b * NN;
#pragma unroll
      for (int it = 0; it < 16; it++) {
        int c = it * 8 + cgrp;
        f16x4 v = *reinterpret_cast<const f16x4*>(&sbuf[c * 132 + nchunk * 4]);
        int hcol = hbase + c;
        int h = hcol >> 6, dcol = hcol & 63;
        *reinterpret_cast<f16x4*>(
            &vT[((size_t)(b * HH + h) * DH + dcol) * NP + n]) = v;
      }
    }
  }
}

// ---------------------------------------------------------------------------
// K2: fused attention, 64 q-rows per WAVE (4 row-groups in register), from
// R15/R14. Swapped-operand MFMA, exp2 domain, deferred normalization,
// coalesced weights write. Grid: 1920, block 256 (4 waves).
// ---------------------------------------------------------------------------
__global__ __launch_bounds__(256) void attn_kernel(
    const f16* __restrict__ q, const f16* __restrict__ karr,
    const f16* __restrict__ vT, float* __restrict__ weights,
    f16* __restrict__ ctx) {
  __shared__ f16 P[4][16][616];  // unnormalized exp2(scores), [rg][row][col]
  __shared__ float redS[4][4][16];     // [rg][wave][row]
  __shared__ float invA_lds[4][16];
  __shared__ float invB_lds[4][16];

  int bid = blockIdx.x;
  int wgid = (bid & 7) * (NWG64 / 8) + (bid >> 3);  // bijective XCD swizzle
  int bh = wgid / NQT, qt = wgid - bh * NQT;

  int tid = threadIdx.x, wid = tid >> 6, lane = tid & 63;
  int lr = lane & 15, lg = lane >> 4;
  int qbase = qt * 64;

  // q fragments for FOUR 16-row groups (rows qbase + g*16 + lr)
  const f16* qr0 = q + ((size_t)bh * NPQ + qbase + lr) * DH;
  f16x8 a[4][2];
#pragma unroll
  for (int g = 0; g < 4; g++) {
    a[g][0] = *reinterpret_cast<const f16x8*>(&qr0[g * 16 * DH + lg * 8]);
    a[g][1] = *reinterpret_cast<const f16x8*>(&qr0[g * 16 * DH + 32 + lg * 8]);
  }

  const f16* kb = karr + (size_t)bh * NP * DH;
  float psA[4] = {0.f, 0.f, 0.f, 0.f}, psB[4] = {0.f, 0.f, 0.f, 0.f};
#pragma unroll
  for (int t = 0; t < TPW; t++) {
    int ct = wid * TPW + t;
    int ctc = ct < NT ? ct : NT - 1;  // clamped (safe) address
    bool live = ct < NT;
    const f16* krp = &kb[(size_t)(ctc * 16 + lr) * DH];
    f16x8 b0 = *reinterpret_cast<const f16x8*>(&krp[lg * 8]);
    f16x8 b1 = *reinterpret_cast<const f16x8*>(&krp[32 + lg * 8]);
#pragma unroll
    for (int g = 0; g < 4; g++) {
      f32x4 acc = {};
      acc = MFMA16(b0, a[g][0], acc);   // S^T: row = k-col, col = q-row
      acc = MFMA16(b1, a[g][1], acc);
      f16x4 pk;
#pragma unroll
      for (int i = 0; i < 4; i++) {
        int col = ct * 16 + lg * 4 + i;   // k column
        bool inA = col < NCLS;
        bool valid = live && (col < NN);
        float e = valid ? __builtin_amdgcn_exp2f(acc[i]) : 0.f;
        if (inA) psA[g] += e; else psB[g] += e;
        pk[i] = (f16)e;
      }
      if (live)
        *reinterpret_cast<f16x4*>(&P[g][lr][ct * 16 + lg * 4]) = pk;
    }
  }
  // reduce across the 4 lanes sharing q-row lr (lanes lr, lr+16, lr+32, lr+48)
#pragma unroll
  for (int g = 0; g < 4; g++) {
    psA[g] += __shfl_xor(psA[g], 16); psA[g] += __shfl_xor(psA[g], 32);
    psB[g] += __shfl_xor(psB[g], 16); psB[g] += __shfl_xor(psB[g], 32);
  }
  if (lane < 16) {
#pragma unroll
    for (int g = 0; g < 4; g++) redS[g][wid][lr] = psB[g];
    if (wid == 0)  // cls cols live entirely in wave 0
#pragma unroll
      for (int g = 0; g < 4; g++) invA_lds[g][lr] = 1.0f / psA[g];
  }
  __syncthreads();
  if (wid == 2 && lane < 16)
#pragma unroll
    for (int g = 0; g < 4; g++)
      invB_lds[g][lr] = 1.0f / (redS[g][0][lr] + redS[g][1][lr] +
                                redS[g][2][lr] + redS[g][3][lr]);
  __syncthreads();

  // weights write: static mapping, each thread: one row per row-group
  {
    int row = tid >> 4, sub = tid & 15;
#pragma unroll
    for (int g = 0; g < 4; g++) {
      int grow = qbase + g * 16 + row;
      if (grow < NN) {
        float iA = invA_lds[g][row];
        float iB = invB_lds[g][row];
        const f16* prow = &P[g][row][0];
        float* wrow = weights + ((size_t)bh * NN + grow) * NN;
#pragma unroll
        for (int k2 = 0; k2 < 10; k2++) {
          int f4 = sub + 16 * k2;
          if (f4 < NN / 4) {
            float inv = (f4 < 5) ? iA : iB;
            f16x4 pv = *reinterpret_cast<const f16x4*>(&prow[f4 * 4]);
            float4 o4 = {(float)pv[0] * inv, (float)pv[1] * inv,
                         (float)pv[2] * inv, (float)pv[3] * inv};
            *reinterpret_cast<float4*>(&wrow[f4 * 4]) = o4;
          }
        }
      }
    }
  }

  // PV (swapped): D[d][q]; each V fragment feeds FOUR row-groups' MFMAs.
  const f16* vrow = vT + (size_t)bh * DH * NP + (size_t)(wid * 16 + lr) * NP;
  f32x4 oA[4] = {}, oB[4] = {};
  {
    f16x8 bv = *reinterpret_cast<const f16x8*>(&vrow[lg * 8]);
#pragma unroll
    for (int g = 0; g < 4; g++) {
      f16x8 pa = *reinterpret_cast<const f16x8*>(&P[g][lr][lg * 8]);
      f16x8 paA = pa, paB = pa;
#pragma unroll
      for (int j = 0; j < 8; j++) {
        if (lg * 8 + j < NCLS) paB[j] = (f16)0.f;
        else paA[j] = (f16)0.f;
      }
      oA[g] = MFMA16(bv, paA, oA[g]);
      oB[g] = MFMA16(bv, paB, oB[g]);
    }
  }
#pragma unroll
  for (int j = 1; j < 19; j++) {
    f16x8 bv = *reinterpret_cast<const f16x8*>(&vrow[j * 32 + lg * 8]);
#pragma unroll
    for (int g = 0; g < 4; g++) {
      f16x8 pa = *reinterpret_cast<const f16x8*>(&P[g][lr][j * 32 + lg * 8]);
      oB[g] = MFMA16(bv, pa, oB[g]);
    }
  }

  // epilogue: lane holds D[d = wid*16 + lg*4 + i][q = lr] for all 4 groups
  int b = bh / HH, h = bh - b * HH;
#pragma unroll
  for (int g = 0; g < 4; g++) {
    int qrow = qbase + g * 16 + lr;
    if (qrow < NN) {
      float iA = invA_lds[g][lr], iB = invB_lds[g][lr];
      f16x4 o4;
#pragma unroll
      for (int i = 0; i < 4; i++) o4[i] = (f16)(oA[g][i] * iA + oB[g][i] * iB);
      *reinterpret_cast<f16x4*>(
          &ctx[((size_t)b * NN + qrow) * CC + h * DH + wid * 16 + lg * 4]) = o4;
    }
  }
}

// ---------------------------------------------------------------------------
// K3: proj GEMM, 128x128x64 tiles, global_load_lds + XOR swizzle.
// NEW: two-pass LDS-staged epilogue (64x128 f32 per pass fits the reused
// 32KB staging buffer) -> float4 coalesced stores (512B per 32 lanes).
// ---------------------------------------------------------------------------
__global__ __launch_bounds__(256) void proj_gemm(
    const f16* __restrict__ ctx, const f16* __restrict__ wT,
    const float* __restrict__ bias, float* __restrict__ out) {
  __shared__ f16 sbuf[128 * 128];      // 32KB: staging (A|B) then f32 C half
  f16* As = sbuf;
  f16* Bs = sbuf + 128 * 64;
  int bn = blockIdx.x, bm = blockIdx.y;
  int tid = threadIdx.x;
  int wid = tid >> 6, lane = tid & 63;
  int wm = wid >> 1, wn = wid & 1;
  int lr = lane & 15, lg = lane >> 4;
  int srcChunk = (lane & 7) ^ (lane >> 3);

  const f16* gA = &ctx[((size_t)bm * 128 + (lane >> 3)) * CC + srcChunk * 8];
  const f16* gB = &wT[((size_t)bn * 128 + (lane >> 3)) * CC + srcChunk * 8];

  f32x4 acc[4][4] = {};
  for (int k0 = 0; k0 < CC; k0 += 64) {
#pragma unroll
    for (int j = 0; j < 4; j++) {
      int r0 = (wid * 4 + j) * 8;
      gload16(gA + (size_t)r0 * CC + k0, &As[r0 * 64]);
      gload16(gB + (size_t)r0 * CC + k0, &Bs[r0 * 64]);
    }
    __syncthreads();
#pragma unroll
    for (int ks = 0; ks < 2; ks++) {
      f16x8 a[4], b[4];
#pragma unroll
      for (int mt = 0; mt < 4; mt++)
        a[mt] = *reinterpret_cast<const f16x8*>(
            &As[(wm * 64 + mt * 16 + lr) * 64 + ((ks * 4 + lg) ^ (lr & 7)) * 8]);
#pragma unroll
      for (int nt = 0; nt < 4; nt++)
        b[nt] = *reinterpret_cast<const f16x8*>(
            &Bs[(wn * 64 + nt * 16 + lr) * 64 + ((ks * 4 + lg) ^ (lr & 7)) * 8]);
#pragma unroll
      for (int mt = 0; mt < 4; mt++)
#pragma unroll
        for (int nt = 0; nt < 4; nt++)
          acc[mt][nt] = MFMA16(a[mt], b[nt], acc[mt][nt]);
    }
    __syncthreads();
  }

  float* fbuf = (float*)sbuf;  // 64x128 f32 = 32KB per pass
#pragma unroll
  for (int pass = 0; pass < 2; pass++) {
    if (pass) __syncthreads();  // fbuf reuse between passes
    if (wm == pass) {
#pragma unroll
      for (int mt = 0; mt < 4; mt++)
#pragma unroll
        for (int nt = 0; nt < 4; nt++) {
          int colL = wn * 64 + nt * 16 + lr;
          float bi = bias[bn * 128 + colL];
#pragma unroll
          for (int i = 0; i < 4; i++) {
            int row = mt * 16 + lg * 4 + i;  // 0..63 within pass
            fbuf[row * 128 + colL] = acc[mt][nt][i] + bi;
          }
        }
    }
    __syncthreads();
    int f4 = tid & 31, rg2 = tid >> 5;
#pragma unroll
    for (int it = 0; it < 8; it++) {
      int row = it * 8 + rg2;
      int m = bm * 128 + pass * 64 + row;
      if (m < MM) {
        float4 v = *reinterpret_cast<const float4*>(&fbuf[row * 128 + f4 * 4]);
        *reinterpret_cast<float4*>(
            &out[(size_t)m * CC + bn * 128 + f4 * 4]) = v;
      }
    }
  }
}

// ---------------------------------------------------------------------------
extern "C" void kernel_launch(void* const* d_in, const int* in_sizes, int n_in,
                              void* d_out, int out_size, void* d_ws,
                              size_t ws_size, hipStream_t stream) {
  const float* x      = (const float*)d_in[0];
  const float* w_qkv  = (const float*)d_in[1];
  const float* b_qkv  = (const float*)d_in[2];
  const float* w_proj = (const float*)d_in[3];
  const float* b_proj = (const float*)d_in[4];

  float* out     = (float*)d_out;
  float* weights = out + (size_t)MM * CC;

  f16* p      = (f16*)d_ws;
  f16* wqkvT  = p;  p += (size_t)K3C * CC;
  f16* wprojT = p;  p += (size_t)CC * CC;
  f16* x16    = p;  p += (size_t)MMP * CC;
  f16* qb     = p;  p += (size_t)BH * NPQ * DH;
  f16* kb     = p;  p += (size_t)BH * NP * DH;
  f16* vT     = p;  p += (size_t)BH * DH * NP;
  f16* ctx    = p;  p += (size_t)MMP * CC;

  prep<<<1728 + 576 + 3600 + 192, 256, 0, stream>>>(w_qkv, w_proj, x, wqkvT,
                                                    wprojT, x16, qb, kb, vT);
  qkv_gemm<<<dim3(K3C / 128, MMP / 128), 256, 0, stream>>>(x16, wqkvT, b_qkv,
                                                           qb, kb, vT);
  attn_kernel<<<NWG64, 256, 0, stream>>>(qb, kb, vT, weights, ctx);
  proj_gemm<<<dim3(CC / 128, MMP / 128), 256, 0, stream>>>(ctx, wprojT, b_proj,
                                                           out);
}